// Round 16
// baseline (154.677 us; speedup 1.0000x reference)
//
#include <hip/hip_runtime.h>
#include <cstdint>
#include <cstddef>

// ---------------------------------------------------------------------------
// GATExtractPart round 16 (base: round 15, 151us; best 150us):
//  - k_ln1 deleted: k_gemm_heads writes hpre=XA@W1+b1 (f16) + global f32
//    row-stat atomics; k_gemm2 applies LN+ReLU during A-staging using the
//    precomputed stats (512 thr, no per-element dots -> round-11 failure
//    causes removed). -1 launch, -134 MB HBM.
// ---------------------------------------------------------------------------

#define LEAKY_SLOPE 0.2f

typedef __attribute__((ext_vector_type(8))) _Float16 half8;
typedef __attribute__((ext_vector_type(4))) float facc4;

// --- merged weight prep ------------------------------------------------------
__global__ void k_prep_w(const float* __restrict__ W1, const float* __restrict__ W2,
                         const float* __restrict__ Wa,
                         const float* __restrict__ We1, const float* __restrict__ ae1,
                         const float* __restrict__ We2, const float* __restrict__ ae2,
                         const float* __restrict__ as1, const float* __restrict__ ad1,
                         _Float16* __restrict__ w1t, _Float16* __restrict__ w2t,
                         _Float16* __restrict__ wat, float* __restrict__ fold) {
    int idx = blockIdx.x * blockDim.x + threadIdx.x;
    if (idx < 1024 * 64) {
        int c = idx >> 6, k = idx & 63;
        w1t[idx] = (k < 55) ? (_Float16)W1[(size_t)k * 1024 + c] : (_Float16)0.f;
        return;
    }
    idx -= 1024 * 64;
    if (idx < 256 * 1024) {
        int c = idx >> 10, k = idx & 1023;
        w2t[idx] = (_Float16)W2[(size_t)k * 256 + c];
        return;
    }
    idx -= 256 * 1024;
    if (idx < 256 * 256) {
        int c = idx >> 8, k = idx & 255;
        int dst = ((c >> 4) * 8 + (k >> 5)) * 512 + ((c & 15) + 16 * ((k >> 3) & 3)) * 8 + (k & 7);
        wat[dst] = (_Float16)Wa[(size_t)k * 256 + c];
        return;
    }
    int t = idx - 256 * 256;
    if (t < 24) {
        int k = t >> 2, h = t & 3;
        float s = 0.f;
        for (int c = 0; c < 256; ++c) s += We1[k * 1024 + h * 256 + c] * ae1[h * 256 + c];
        fold[t] = s;
    } else if (t < 30) {
        int k = t - 24;
        float s = 0.f;
        for (int c = 0; c < 256; ++c) s += We2[k * 256 + c] * ae2[c];
        fold[32 + k] = s;
    } else if (t >= 64 && t < 284) {
        int i = t - 64, k = i >> 2, h = i & 3;
        float s = 0.f;
        for (int c = 0; c < 256; ++c) s += W1[k * 1024 + h * 256 + c] * as1[h * 256 + c];
        fold[64 + i] = s;
    } else if (t >= 320 && t < 540) {
        int i = t - 320, k = i >> 2, h = i & 3;
        float s = 0.f;
        for (int c = 0; c < 256; ++c) s += W1[k * 1024 + h * 256 + c] * ad1[h * 256 + c];
        fold[320 + i] = s;
    }
}

// --- merged x prep: fragment-order cast + folded ss1/sd1 --------------------
__global__ void k_prep_x(const float* __restrict__ x, const float* __restrict__ wa1,
                         const float* __restrict__ wd1, _Float16* __restrict__ xbf,
                         float* __restrict__ ss1, float* __restrict__ sd1, int N) {
    int idx = blockIdx.x * blockDim.x + threadIdx.x;
    if (idx < N * 64) {
        int n = idx >> 6, k = idx & 63;
        _Float16 v = (k < 55) ? (_Float16)x[(size_t)n * 55 + k] : (_Float16)0.f;
        int g = n >> 6, nl = n & 63;
        size_t dst = (size_t)g * 4096 +
                     (((k >> 4) * 2 + (nl >> 5)) * 512 +
                      ((k & 15) + 16 * ((nl >> 3) & 3)) * 8 + (nl & 7));
        xbf[dst] = v;
        return;
    }
    int n = idx - N * 64;
    if (n >= N) return;
    float a0 = 0, a1 = 0, a2 = 0, a3 = 0, d0 = 0, d1 = 0, d2 = 0, d3 = 0;
    for (int k = 0; k < 55; ++k) {
        float xv = x[(size_t)n * 55 + k];
        float4 wa = *reinterpret_cast<const float4*>(&wa1[k * 4]);
        float4 wd = *reinterpret_cast<const float4*>(&wd1[k * 4]);
        a0 += xv * wa.x; a1 += xv * wa.y; a2 += xv * wa.z; a3 += xv * wa.w;
        d0 += xv * wd.x; d1 += xv * wd.y; d2 += xv * wd.z; d3 += xv * wd.w;
    }
    *reinterpret_cast<float4*>(&ss1[n * 4]) = make_float4(a0, a1, a2, a3);
    *reinterpret_cast<float4*>(&sd1[n * 4]) = make_float4(d0, d1, d2, d3);
}

// --- per-graph CSR + edge-attr dots, all in LDS ------------------------------
__global__ __launch_bounds__(256) void k_graph_csr(
    const int* __restrict__ ei, const float* __restrict__ ea,
    const float* __restrict__ we1, const float* __restrict__ we2,
    int* __restrict__ coff, int* __restrict__ eid,
    float* __restrict__ ead1, float* __restrict__ ead2, int E, int B) {
    __shared__ int degL[64];
    __shared__ float meaL[64][6];
    __shared__ int cs[65];
    __shared__ int fillL[64];
    int g = blockIdx.x;
    int ng = g * 64;
    int e0 = g * 256;
    int tid = threadIdx.x;
    if (tid < 64) {
        degL[tid] = 0; fillL[tid] = 0;
#pragma unroll
        for (int k = 0; k < 6; ++k) meaL[tid][k] = 0.f;
    }
    __syncthreads();
    int eg = e0 + tid;
    int dst = ei[E + eg];
    int dl = dst - ng;
    atomicAdd(&degL[dl], 1);
#pragma unroll
    for (int k = 0; k < 6; ++k) atomicAdd(&meaL[dl][k], ea[(size_t)eg * 6 + k]);
    __syncthreads();
    if (tid < 64) {
        int v = degL[tid] + 1;
        int incl = v;
#pragma unroll
        for (int o = 1; o < 64; o <<= 1) {
            int up = __shfl_up(incl, o);
            if (tid >= o) incl += up;
        }
        cs[tid + 1] = incl;
        if (tid == 0) cs[0] = 0;
        coff[ng + tid] = g * 320 + (incl - v);
        if (g == B - 1 && tid == 63) coff[ng + 64] = (g + 1) * 320;
    }
    __syncthreads();
    {
        float v[4] = {};
        float v2 = 0.f;
        const float* eap = ea + (size_t)eg * 6;
#pragma unroll
        for (int k = 0; k < 6; ++k) {
            float a = eap[k];
#pragma unroll
            for (int h = 0; h < 4; ++h) v[h] += a * we1[k * 4 + h];
            v2 += a * we2[k];
        }
#pragma unroll
        for (int h = 0; h < 4; ++h) ead1[(size_t)eg * 4 + h] = v[h];
        ead2[eg] = v2;
        int pos = cs[dl] + atomicAdd(&fillL[dl], 1);
        eid[g * 320 + pos] = eg;
    }
    if (tid < 64) {
        float inv = 1.f / fmaxf((float)degL[tid], 1.f);
        float v[4] = {};
        float v2 = 0.f;
#pragma unroll
        for (int k = 0; k < 6; ++k) {
            float a = meaL[tid][k] * inv;
#pragma unroll
            for (int h = 0; h < 4; ++h) v[h] += a * we1[k * 4 + h];
            v2 += a * we2[k];
        }
        int se = E + ng + tid;
#pragma unroll
        for (int h = 0; h < 4; ++h) ead1[(size_t)se * 4 + h] = v[h];
        ead2[se] = v2;
        int pos = cs[tid] + atomicAdd(&fillL[tid], 1);
        eid[g * 320 + pos] = se;
    }
}

__global__ __launch_bounds__(512) void k_pbuild1(
    const _Float16* __restrict__ xbf,
    const int* __restrict__ coff, const int* __restrict__ eid, const int* __restrict__ ei,
    const float* __restrict__ ead1, const float* __restrict__ ss1,
    const float* __restrict__ sd1,
    _Float16* __restrict__ XA, int ldxa, int E, int g0) {
    __shared__ _Float16 Pm[4][64 * 64];
    __shared__ float llds[384][4];
    __shared__ int slds[384];
    int g = blockIdx.x;
    int ng = (g0 + g) * 64;
    int lr0 = g * 64;
    int tid = threadIdx.x;
    int lane = tid & 63, wid = tid >> 6;
    int l15 = lane & 15, l4 = lane >> 4;
    for (int i = tid; i < 4 * 64 * 64 / 8; i += 512)
        *reinterpret_cast<int4*>(&Pm[0][0] + i * 8) = int4{0, 0, 0, 0};
    int pbase = coff[ng];
    int pcnt = coff[ng + 64] - pbase;
    if (pcnt > 384) pcnt = 384;
    for (int p = tid; p < pcnt; p += 512) {
        int e = eid[pbase + p];
        int s, d;
        if (e < E) { s = ei[e]; d = ei[E + e]; } else { s = e - E; d = s; }
        slds[p] = s - ng;
        float4 sv = *reinterpret_cast<const float4*>(&ss1[s * 4]);
        float4 dv = *reinterpret_cast<const float4*>(&sd1[d * 4]);
        float4 ev = *reinterpret_cast<const float4*>(&ead1[(size_t)e * 4]);
        float v0 = sv.x + dv.x + ev.x, v1 = sv.y + dv.y + ev.y;
        float v2 = sv.z + dv.z + ev.z, v3 = sv.w + dv.w + ev.w;
        llds[p][0] = (v0 > 0.f) ? v0 : LEAKY_SLOPE * v0;
        llds[p][1] = (v1 > 0.f) ? v1 : LEAKY_SLOPE * v1;
        llds[p][2] = (v2 > 0.f) ? v2 : LEAKY_SLOPE * v2;
        llds[p][3] = (v3 > 0.f) ? v3 : LEAKY_SLOPE * v3;
    }
    __syncthreads();
    if (tid < 256) {
        int dst = tid >> 2, h = tid & 3;
        int p0 = coff[ng + dst] - pbase, p1 = coff[ng + dst + 1] - pbase;
        float m = -1e30f;
        for (int p = p0; p < p1; ++p) m = fmaxf(m, llds[p][h]);
        float sm = 0.f;
        for (int p = p0; p < p1; ++p) sm += expf(llds[p][h] - m);
        float iv = 1.f / (sm + 1e-16f);
        for (int p = p0; p < p1; ++p) {
            int src = slds[p];
            int pos = dst * 64 + (((src >> 3) ^ (dst & 7)) << 3) + (src & 7);
            Pm[h][pos] = (_Float16)((float)Pm[h][pos] + expf(llds[p][h] - m) * iv);
        }
    }
    __syncthreads();
    int head = wid >> 1, fjh = wid & 1;
    const _Float16* xg = xbf + (size_t)(g0 + g) * 4096;
    facc4 acc[4][2] = {};
#pragma unroll
    for (int kk = 0; kk < 2; ++kk) {
        half8 af[4], bf[2];
#pragma unroll
        for (int f = 0; f < 4; ++f) {
            int arow = f * 16 + l15;
            af[f] = *reinterpret_cast<const half8*>(
                &Pm[head][arow * 64 + (((kk * 4 + l4) ^ (arow & 7)) << 3)]);
        }
#pragma unroll
        for (int f = 0; f < 2; ++f)
            bf[f] = *reinterpret_cast<const half8*>(
                xg + (((fjh * 2 + f) * 2 + kk) * 512 + lane * 8));
#pragma unroll
        for (int fi = 0; fi < 4; ++fi)
#pragma unroll
            for (int fj = 0; fj < 2; ++fj)
                acc[fi][fj] = __builtin_amdgcn_mfma_f32_16x16x32_f16(
                    af[fi], bf[fj], acc[fi][fj], 0, 0, 0);
    }
#pragma unroll
    for (int fi = 0; fi < 4; ++fi)
#pragma unroll
        for (int fj = 0; fj < 2; ++fj)
#pragma unroll
            for (int i = 0; i < 4; ++i) {
                int r = fi * 16 + l4 * 4 + i;
                int k2 = fjh * 32 + fj * 16 + l15;
                XA[((size_t)head * ldxa + lr0 + r) * 64 + k2] = (_Float16)acc[fi][fj][i];
            }
}

// --- hpre = XA@W1 + b1 (f16), plus per-row sum/sumsq atomics -----------------
__global__ __launch_bounds__(256) void k_gemm_heads(
    const _Float16* __restrict__ XA, int ldxa, const _Float16* __restrict__ w1t,
    const float* __restrict__ b1, _Float16* __restrict__ hpre,
    float* __restrict__ rsum, float* __restrict__ rsq) {
    int h = blockIdx.z;
    const _Float16* A = XA + (size_t)h * ldxa * 64;
    const _Float16* BT = w1t + (size_t)h * 256 * 64;
    __shared__ _Float16 As[128 * 64];
    __shared__ _Float16 Bs[128 * 64];
    int tid = threadIdx.x;
    int lane = tid & 63, wid = tid >> 6;
    int wr = wid >> 1, wc = wid & 1;
    int l15 = lane & 15, l4 = lane >> 4;
    int r0 = blockIdx.y * 128, c0 = blockIdx.x * 128;
    facc4 acc[4][4] = {};
#pragma unroll
    for (int i = 0; i < 4; ++i) {
        int ch = tid + 256 * i;
        int row = ch >> 3, col16 = ch & 7;
        int sw = col16 ^ (row & 7);
        *reinterpret_cast<int4*>(&As[row * 64 + sw * 8]) =
            *reinterpret_cast<const int4*>(A + (size_t)(r0 + row) * 64 + col16 * 8);
        *reinterpret_cast<int4*>(&Bs[row * 64 + sw * 8]) =
            *reinterpret_cast<const int4*>(BT + (size_t)(c0 + row) * 64 + col16 * 8);
    }
    __syncthreads();
#pragma unroll
    for (int kk = 0; kk < 2; ++kk) {
        half8 af[4], bf[4];
#pragma unroll
        for (int f = 0; f < 4; ++f) {
            int arow = wr * 64 + f * 16 + l15;
            int ac = (kk * 4 + l4) ^ (arow & 7);
            af[f] = *reinterpret_cast<const half8*>(&As[arow * 64 + ac * 8]);
            int brow = wc * 64 + f * 16 + l15;
            int bc = (kk * 4 + l4) ^ (brow & 7);
            bf[f] = *reinterpret_cast<const half8*>(&Bs[brow * 64 + bc * 8]);
        }
#pragma unroll
        for (int fi = 0; fi < 4; ++fi)
#pragma unroll
            for (int fj = 0; fj < 4; ++fj)
                acc[fi][fj] = __builtin_amdgcn_mfma_f32_16x16x32_f16(
                    af[fi], bf[fj], acc[fi][fj], 0, 0, 0);
    }
    float bb[4];
#pragma unroll
    for (int fj = 0; fj < 4; ++fj) bb[fj] = b1[h * 256 + c0 + wc * 64 + fj * 16 + l15];
#pragma unroll
    for (int fi = 0; fi < 4; ++fi)
#pragma unroll
        for (int i = 0; i < 4; ++i) {
            int r = r0 + wr * 64 + fi * 16 + l4 * 4 + i;
            float s = 0.f, q = 0.f;
#pragma unroll
            for (int fj = 0; fj < 4; ++fj) {
                int cc = h * 256 + c0 + wc * 64 + fj * 16 + l15;
                float v = acc[fi][fj][i] + bb[fj];
                hpre[(size_t)r * 1024 + cc] = (_Float16)v;
                s += v; q += v * v;
            }
            s += __shfl_xor(s, 1); q += __shfl_xor(q, 1);
            s += __shfl_xor(s, 2); q += __shfl_xor(q, 2);
            s += __shfl_xor(s, 4); q += __shfl_xor(q, 4);
            s += __shfl_xor(s, 8); q += __shfl_xor(q, 8);
            if (l15 == 0) { atomicAdd(&rsum[r], s); atomicAdd(&rsq[r], q); }
        }
}

// --- GEMM2: LN+ReLU on A-staging; h2f frag-order; ss2/sd2 epilogue -----------
__global__ __launch_bounds__(512) void k_gemm2(
    const _Float16* __restrict__ hpre, const _Float16* __restrict__ BT,
    const float* __restrict__ rsum, const float* __restrict__ rsq,
    const float* __restrict__ g1, const float* __restrict__ be1,
    const float* __restrict__ as2, const float* __restrict__ ad2,
    _Float16* __restrict__ h2f, float* __restrict__ ss2, float* __restrict__ sd2,
    int n0) {
    __shared__ _Float16 As[128 * 64];
    __shared__ _Float16 Bs[256 * 64];
    __shared__ float mus[128], rstds[128], s2L[128], d2L[128];
    int tid = threadIdx.x;
    int lane = tid & 63, wid = tid >> 6;
    int wr = wid >> 2, wc = wid & 3;
    int l15 = lane & 15, l4 = lane >> 4;
    int r0 = blockIdx.x * 128;
    if (tid < 128) {
        float mu = rsum[r0 + tid] * (1.f / 1024.f);
        float var = rsq[r0 + tid] * (1.f / 1024.f) - mu * mu;
        mus[tid] = mu;
        rstds[tid] = rsqrtf(var + 1e-5f);
        s2L[tid] = 0.f; d2L[tid] = 0.f;
    }
    __syncthreads();
    facc4 acc[4][4] = {};
    for (int kt = 0; kt < 1024; kt += 64) {
#pragma unroll
        for (int i = 0; i < 2; ++i) {
            int ch = tid + 512 * i;
            int row = ch >> 3, col16 = ch & 7;
            int sw = col16 ^ (row & 7);
            half8 hv = *reinterpret_cast<const half8*>(
                hpre + (size_t)(r0 + row) * 1024 + kt + col16 * 8);
            float mu = mus[row], rs = rstds[row];
            half8 ov;
#pragma unroll
            for (int j = 0; j < 8; ++j) {
                int c = kt + col16 * 8 + j;
                ov[j] = (_Float16)fmaxf(((float)hv[j] - mu) * rs * g1[c] + be1[c], 0.f);
            }
            *reinterpret_cast<half8*>(&As[row * 64 + sw * 8]) = ov;
        }
#pragma unroll
        for (int i = 0; i < 4; ++i) {
            int ch = tid + 512 * i;
            int row = ch >> 3, col16 = ch & 7;
            int sw = col16 ^ (row & 7);
            *reinterpret_cast<int4*>(&Bs[row * 64 + sw * 8]) =
                *reinterpret_cast<const int4*>(BT + (size_t)row * 1024 + kt + col16 * 8);
        }
        __syncthreads();
#pragma unroll
        for (int kk = 0; kk < 2; ++kk) {
            half8 af[4], bf[4];
#pragma unroll
            for (int f = 0; f < 4; ++f) {
                int arow = wr * 64 + f * 16 + l15;
                int ac = (kk * 4 + l4) ^ (arow & 7);
                af[f] = *reinterpret_cast<const half8*>(&As[arow * 64 + ac * 8]);
                int brow = wc * 64 + f * 16 + l15;
                int bc = (kk * 4 + l4) ^ (brow & 7);
                bf[f] = *reinterpret_cast<const half8*>(&Bs[brow * 64 + bc * 8]);
            }
#pragma unroll
            for (int fi = 0; fi < 4; ++fi)
#pragma unroll
                for (int fj = 0; fj < 4; ++fj)
                    acc[fi][fj] = __builtin_amdgcn_mfma_f32_16x16x32_f16(
                        af[fi], bf[fj], acc[fi][fj], 0, 0, 0);
        }
        __syncthreads();
    }
#pragma unroll
    for (int fi = 0; fi < 4; ++fi)
#pragma unroll
        for (int i = 0; i < 4; ++i) {
            float s2 = 0.f, d2 = 0.f;
#pragma unroll
            for (int fj = 0; fj < 4; ++fj) {
                int r = r0 + wr * 64 + fi * 16 + l4 * 4 + i;
                int cc = wc * 64 + fj * 16 + l15;
                float v = acc[fi][fj][i];
                int g = r >> 6, nl = r & 63;
                size_t dst = (size_t)g * 16384 +
                             (((cc >> 4) * 2 + (nl >> 5)) * 512 +
                              ((cc & 15) + 16 * ((nl >> 3) & 3)) * 8 + (nl & 7));
                h2f[dst] = (_Float16)v;
                s2 += v * as2[cc];
                d2 += v * ad2[cc];
            }
            s2 += __shfl_xor(s2, 1); d2 += __shfl_xor(d2, 1);
            s2 += __shfl_xor(s2, 2); d2 += __shfl_xor(d2, 2);
            s2 += __shfl_xor(s2, 4); d2 += __shfl_xor(d2, 4);
            s2 += __shfl_xor(s2, 8); d2 += __shfl_xor(d2, 8);
            if (l15 == 0) {
                int rl = wr * 64 + fi * 16 + l4 * 4 + i;
                atomicAdd(&s2L[rl], s2);
                atomicAdd(&d2L[rl], d2);
            }
        }
    __syncthreads();
    if (tid < 128) {
        ss2[n0 + r0 + tid] = s2L[tid];
        sd2[n0 + r0 + tid] = d2L[tid];
    }
}

// --- merged layer-2 + scores + softmax + pool + emb (per graph) --------------
__global__ __launch_bounds__(512) void k_graph2f(
    const _Float16* __restrict__ h2f,
    const int* __restrict__ coff, const int* __restrict__ eid, const int* __restrict__ ei,
    const float* __restrict__ ead2, const float* __restrict__ ss2g,
    const float* __restrict__ sd2g,
    const float* __restrict__ b2, const float* __restrict__ g2,
    const float* __restrict__ be2,
    const _Float16* __restrict__ wat, const float* __restrict__ va,
    const int* __restrict__ food, const float* __restrict__ emb,
    float* __restrict__ out, int E, int B, int g0) {
    __shared__ _Float16 hfL[64 * 256];       // 32 KB arena
    _Float16* Pm = hfL;
    float* Pf = reinterpret_cast<float*>(hfL + 4096);
    float* llds = reinterpret_cast<float*>(hfL + 12288);
    int* slds = reinterpret_cast<int*>(hfL + 12288 + 640);
    int* dlds = reinterpret_cast<int*>(hfL + 12288 + 1280);
    float* mL  = reinterpret_cast<float*>(hfL + 12288 + 1920);
    float* ivL = reinterpret_cast<float*>(hfL + 12288 + 2048);
    __shared__ float rsum[64], rsq[64];
    __shared__ float part[8][64];
    __shared__ float at[64];
    int g = blockIdx.x;
    int b = g0 + g;
    int ng = (g0 + g) * 64;
    int tid = threadIdx.x;
    int lane = tid & 63, wid = tid >> 6;
    int l15 = lane & 15, l4 = lane >> 4;
    int cbase = wid * 32;
    if (tid < 64) { rsum[tid] = 0.f; rsq[tid] = 0.f; }
    for (int i = tid; i < 1024; i += 512)
        reinterpret_cast<int4*>(Pf)[i] = int4{0, 0, 0, 0};
    const _Float16* hg = h2f + (size_t)g * 16384;
    half8 bfr[2][2];
#pragma unroll
    for (int kk = 0; kk < 2; ++kk)
#pragma unroll
        for (int f = 0; f < 2; ++f)
            bfr[kk][f] = *reinterpret_cast<const half8*>(
                hg + ((((cbase + f * 16) >> 4) * 2 + kk) * 512 + lane * 8));
    int pbase = coff[ng];
    int pcnt = coff[ng + 64] - pbase;
    if (pcnt > 384) pcnt = 384;
    for (int p = tid; p < pcnt; p += 512) {
        int e = eid[pbase + p];
        int s, d;
        if (e < E) { s = ei[e]; d = ei[E + e]; } else { s = e - E; d = s; }
        slds[p] = s - ng;
        dlds[p] = d - ng;
        float v = ss2g[s] + sd2g[d] + ead2[e];
        llds[p] = (v > 0.f) ? v : LEAKY_SLOPE * v;
    }
    __syncthreads();
    {
        int dst = tid >> 3, sub = tid & 7;
        int p0 = coff[ng + dst] - pbase, p1 = coff[ng + dst + 1] - pbase;
        float m = -1e30f;
        for (int p = p0 + sub; p < p1; p += 8) m = fmaxf(m, llds[p]);
        m = fmaxf(m, __shfl_xor(m, 1));
        m = fmaxf(m, __shfl_xor(m, 2));
        m = fmaxf(m, __shfl_xor(m, 4));
        float sm = 0.f;
        for (int p = p0 + sub; p < p1; p += 8) sm += expf(llds[p] - m);
        sm += __shfl_xor(sm, 1);
        sm += __shfl_xor(sm, 2);
        sm += __shfl_xor(sm, 4);
        if (sub == 0) { mL[dst] = m; ivL[dst] = 1.f / (sm + 1e-16f); }
    }
    __syncthreads();
    for (int p = tid; p < pcnt; p += 512) {
        int d = dlds[p];
        int src = slds[p];
        float a = expf(llds[p] - mL[d]) * ivL[d];
        atomicAdd(&Pf[d * 64 + (((src >> 3) ^ (d & 7)) << 3) + (src & 7)], a);
    }
    __syncthreads();
    {
        float4 a = reinterpret_cast<const float4*>(Pf)[tid * 2];
        float4 c = reinterpret_cast<const float4*>(Pf)[tid * 2 + 1];
        half8 o;
        o[0] = (_Float16)a.x; o[1] = (_Float16)a.y; o[2] = (_Float16)a.z; o[3] = (_Float16)a.w;
        o[4] = (_Float16)c.x; o[5] = (_Float16)c.y; o[6] = (_Float16)c.z; o[7] = (_Float16)c.w;
        __syncthreads();
        *reinterpret_cast<half8*>(&Pm[tid * 8]) = o;
    }
    __syncthreads();
    facc4 acc[4][2] = {};
#pragma unroll
    for (int kk = 0; kk < 2; ++kk) {
        half8 af[4];
#pragma unroll
        for (int f = 0; f < 4; ++f) {
            int arow = f * 16 + l15;
            af[f] = *reinterpret_cast<const half8*>(
                &Pm[arow * 64 + (((kk * 4 + l4) ^ (arow & 7)) << 3)]);
        }
#pragma unroll
        for (int fi = 0; fi < 4; ++fi)
#pragma unroll
            for (int fj = 0; fj < 2; ++fj)
                acc[fi][fj] = __builtin_amdgcn_mfma_f32_16x16x32_f16(
                    af[fi], bfr[kk][fj], acc[fi][fj], 0, 0, 0);
    }
    float bb[2];
#pragma unroll
    for (int fj = 0; fj < 2; ++fj) bb[fj] = b2[cbase + fj * 16 + l15];
#pragma unroll
    for (int fi = 0; fi < 4; ++fi)
#pragma unroll
        for (int i = 0; i < 4; ++i) {
            float s = 0.f, q = 0.f;
#pragma unroll
            for (int fj = 0; fj < 2; ++fj) {
                float v = acc[fi][fj][i] + bb[fj];
                acc[fi][fj][i] = v;
                s += v; q += v * v;
            }
            s += __shfl_xor(s, 1); q += __shfl_xor(q, 1);
            s += __shfl_xor(s, 2); q += __shfl_xor(q, 2);
            s += __shfl_xor(s, 4); q += __shfl_xor(q, 4);
            s += __shfl_xor(s, 8); q += __shfl_xor(q, 8);
            if (l15 == 0) {
                int r = fi * 16 + l4 * 4 + i;
                atomicAdd(&rsum[r], s);
                atomicAdd(&rsq[r], q);
            }
        }
    __syncthreads();
#pragma unroll
    for (int fi = 0; fi < 4; ++fi)
#pragma unroll
        for (int i = 0; i < 4; ++i) {
            int rl = l4 * 4 + i;
            float mu = rsum[fi * 16 + rl] * (1.f / 256.f);
            float var = rsq[fi * 16 + rl] * (1.f / 256.f) - mu * mu;
            float rstd = rsqrtf(var + 1e-5f);
#pragma unroll
            for (int fj = 0; fj < 2; ++fj) {
                int c = cbase + fj * 16 + l15;
                float v = (acc[fi][fj][i] - mu) * rstd * g2[c] + be2[c];
                acc[fi][fj][i] = v;
                int idx = (fi * 8 + wid) * 512 +
                          ((fj * 2 + (l15 >> 3)) * 16 + rl) * 8 + (l15 & 7);
                hfL[idx] = (_Float16)v;
            }
        }
    __syncthreads();
    facc4 acc2[4][2] = {};
#pragma unroll
    for (int kk = 0; kk < 8; ++kk) {
        half8 af[4], bf[2];
#pragma unroll
        for (int f = 0; f < 4; ++f)
            af[f] = *reinterpret_cast<const half8*>(&hfL[(f * 8 + kk) * 512 + lane * 8]);
#pragma unroll
        for (int f = 0; f < 2; ++f)
            bf[f] = *reinterpret_cast<const half8*>(
                wat + (((wid * 2 + f) * 8 + kk) * 512 + lane * 8));
#pragma unroll
        for (int fi = 0; fi < 4; ++fi)
#pragma unroll
            for (int fj = 0; fj < 2; ++fj)
                acc2[fi][fj] = __builtin_amdgcn_mfma_f32_16x16x32_f16(
                    af[fi], bf[fj], acc2[fi][fj], 0, 0, 0);
    }
    float vac[2];
#pragma unroll
    for (int fj = 0; fj < 2; ++fj) vac[fj] = va[cbase + fj * 16 + l15];
#pragma unroll
    for (int fi = 0; fi < 4; ++fi)
#pragma unroll
        for (int i = 0; i < 4; ++i) {
            float v = tanhf(acc2[fi][0][i]) * vac[0] + tanhf(acc2[fi][1][i]) * vac[1];
            v += __shfl_xor(v, 1); v += __shfl_xor(v, 2);
            v += __shfl_xor(v, 4); v += __shfl_xor(v, 8);
            if (l15 == 0) part[wid][fi * 16 + l4 * 4 + i] = v;
        }
    __syncthreads();
    if (tid < 64) {
        float sc = part[0][tid] + part[1][tid] + part[2][tid] + part[3][tid] +
                   part[4][tid] + part[5][tid] + part[6][tid] + part[7][tid];
        float m = sc;
        for (int o = 32; o; o >>= 1) m = fmaxf(m, __shfl_xor(m, o));
        float ex = expf(sc - m);
        float s = ex;
        for (int o = 32; o; o >>= 1) s += __shfl_xor(s, o);
        float a = ex / (s + 1e-16f);
        at[tid] = a;
        out[(size_t)B * 512 + (size_t)b * 64 + tid] = a;
    }
    __syncthreads();
#pragma unroll
    for (int fj = 0; fj < 2; ++fj) {
        float m = -1e30f;
#pragma unroll
        for (int fi = 0; fi < 4; ++fi)
#pragma unroll
            for (int i = 0; i < 4; ++i) {
                int r = fi * 16 + l4 * 4 + i;
                m = fmaxf(m, acc[fi][fj][i] * at[r]);
            }
        m = fmaxf(m, __shfl_xor(m, 16));
        m = fmaxf(m, __shfl_xor(m, 32));
        if (l4 == 0)
            out[(size_t)b * 256 + cbase + fj * 16 + l15] = m;
    }
    if (tid < 256)
        out[(size_t)B * 256 + (size_t)b * 256 + tid] =
            emb[(size_t)food[b] * 256 + tid];
}

// ---------------------------------------------------------------------------
extern "C" void kernel_launch(void* const* d_in, const int* in_sizes, int n_in,
                              void* d_out, int out_size, void* d_ws, size_t ws_size,
                              hipStream_t stream) {
    const float* x   = (const float*)d_in[0];
    const float* ea  = (const float*)d_in[1];
    const int*   ei  = (const int*)d_in[2];
    const int*   food= (const int*)d_in[4];
    const float* W1  = (const float*)d_in[5];
    const float* as1 = (const float*)d_in[6];
    const float* ad1 = (const float*)d_in[7];
    const float* We1 = (const float*)d_in[8];
    const float* ae1 = (const float*)d_in[9];
    const float* b1  = (const float*)d_in[10];
    const float* g1  = (const float*)d_in[11];
    const float* be1 = (const float*)d_in[12];
    const float* W2  = (const float*)d_in[13];
    const float* as2 = (const float*)d_in[14];
    const float* ad2 = (const float*)d_in[15];
    const float* We2 = (const float*)d_in[16];
    const float* ae2 = (const float*)d_in[17];
    const float* b2  = (const float*)d_in[18];
    const float* g2  = (const float*)d_in[19];
    const float* be2 = (const float*)d_in[20];
    const float* Wa  = (const float*)d_in[21];
    const float* va  = (const float*)d_in[22];
    const float* emb = (const float*)d_in[23];
    float* out = (float*)d_out;

    const int N  = in_sizes[0] / 55;
    const int E  = in_sizes[2] / 2;
    const int B  = in_sizes[4];
    const int Ef = E + N;
    const int LPG = N / B;

    char* w = (char*)d_ws;
    size_t off = 0;
    auto take = [&](size_t bytes) -> char* {
        char* p = w + off;
        off = (off + bytes + 255) & ~(size_t)255;
        return p;
    };
    int*      coff = (int*)take((size_t)(N + 1) * 4);
    int*      eid  = (int*)take((size_t)Ef * 4);
    float*    ead1 = (float*)take((size_t)Ef * 4 * 4);
    float*    ead2 = (float*)take((size_t)Ef * 4);
    float*    fold = (float*)take(4096 * 4);
    float*    ss1  = (float*)take((size_t)N * 4 * 4);
    float*    sd1  = (float*)take((size_t)N * 4 * 4);
    float*    ss2  = (float*)take((size_t)N * 4);
    float*    sd2  = (float*)take((size_t)N * 4);
    float*    rsum = (float*)take((size_t)N * 4);
    float*    rsq  = (float*)take((size_t)N * 4);
    _Float16* xbf  = (_Float16*)take((size_t)N * 64 * 2);
    _Float16* w1t  = (_Float16*)take((size_t)1024 * 64 * 2);
    _Float16* w2t  = (_Float16*)take((size_t)256 * 1024 * 2);
    _Float16* wat  = (_Float16*)take((size_t)256 * 256 * 2);
    size_t smallEnd = off;

    int G = B;
    while (G > 2 && smallEnd + (size_t)G * 32768 + 2ull * G * 131072 + 768 > ws_size) G >>= 1;
    _Float16* XA   = (_Float16*)take((size_t)G * 32768);
    _Float16* hpre = (_Float16*)take((size_t)G * 131072);
    _Float16* h2f  = (_Float16*)take((size_t)G * 131072);   // in old hln region

    k_prep_w<<<(1024 * 64 + 256 * 1024 + 256 * 256 + 3072 + 255) / 256, 256, 0, stream>>>(
        W1, W2, Wa, We1, ae1, We2, ae2, as1, ad1, w1t, w2t, wat, fold);
    k_prep_x<<<(N * 64 + N + 255) / 256, 256, 0, stream>>>(
        x, fold + 64, fold + 320, xbf, ss1, sd1, N);
    k_graph_csr<<<B, 256, 0, stream>>>(ei, ea, fold, fold + 32, coff, eid,
                                       ead1, ead2, E, B);

    for (int g0 = 0; g0 < B; g0 += G) {
        int Gc = (g0 + G <= B) ? G : (B - g0);
        int n0 = g0 * LPG;
        int NC = Gc * LPG;
        hipMemsetAsync(rsum, 0, (size_t)NC * 4, stream);
        hipMemsetAsync(rsq, 0, (size_t)NC * 4, stream);
        k_pbuild1<<<Gc, 512, 0, stream>>>(xbf, coff, eid, ei, ead1, ss1, sd1,
                                          XA, NC, E, g0);
        k_gemm_heads<<<dim3(2, NC / 128, 4), 256, 0, stream>>>(XA, NC, w1t, b1,
                                                               hpre, rsum, rsq);
        k_gemm2<<<NC / 128, 512, 0, stream>>>(hpre, w2t, rsum, rsq, g1, be1,
                                              as2, ad2, h2f, ss2, sd2, n0);
        k_graph2f<<<Gc, 512, 0, stream>>>(h2f, coff, eid, ei, ead2, ss2, sd2,
                                          b2, g2, be2, wat, va, food, emb,
                                          out, E, B, g0);
    }
}

// Round 17
// 151.183 us; speedup vs baseline: 1.0231x; 1.0231x over previous
//
#include <hip/hip_runtime.h>
#include <cstdint>
#include <cstddef>

// ---------------------------------------------------------------------------
// GATExtractPart round 17: revert to round-14 configuration (measured best,
// 150.4us). Rounds 15/16 variants (wave-parallel softmax, LN-in-staging)
// were neutral/regressive; per-graph chain is latency-bound at grid=B=512.
// ---------------------------------------------------------------------------

#define LEAKY_SLOPE 0.2f

typedef __attribute__((ext_vector_type(8))) _Float16 half8;
typedef __attribute__((ext_vector_type(4))) float facc4;

// --- merged weight prep ------------------------------------------------------
__global__ void k_prep_w(const float* __restrict__ W1, const float* __restrict__ W2,
                         const float* __restrict__ Wa,
                         const float* __restrict__ We1, const float* __restrict__ ae1,
                         const float* __restrict__ We2, const float* __restrict__ ae2,
                         const float* __restrict__ as1, const float* __restrict__ ad1,
                         _Float16* __restrict__ w1t, _Float16* __restrict__ w2t,
                         _Float16* __restrict__ wat, float* __restrict__ fold) {
    int idx = blockIdx.x * blockDim.x + threadIdx.x;
    if (idx < 1024 * 64) {
        int c = idx >> 6, k = idx & 63;
        w1t[idx] = (k < 55) ? (_Float16)W1[(size_t)k * 1024 + c] : (_Float16)0.f;
        return;
    }
    idx -= 1024 * 64;
    if (idx < 256 * 1024) {
        int c = idx >> 10, k = idx & 1023;
        w2t[idx] = (_Float16)W2[(size_t)k * 256 + c];
        return;
    }
    idx -= 256 * 1024;
    if (idx < 256 * 256) {
        int c = idx >> 8, k = idx & 255;
        int dst = ((c >> 4) * 8 + (k >> 5)) * 512 + ((c & 15) + 16 * ((k >> 3) & 3)) * 8 + (k & 7);
        wat[dst] = (_Float16)Wa[(size_t)k * 256 + c];
        return;
    }
    int t = idx - 256 * 256;
    if (t < 24) {
        int k = t >> 2, h = t & 3;
        float s = 0.f;
        for (int c = 0; c < 256; ++c) s += We1[k * 1024 + h * 256 + c] * ae1[h * 256 + c];
        fold[t] = s;
    } else if (t < 30) {
        int k = t - 24;
        float s = 0.f;
        for (int c = 0; c < 256; ++c) s += We2[k * 256 + c] * ae2[c];
        fold[32 + k] = s;
    } else if (t >= 64 && t < 284) {
        int i = t - 64, k = i >> 2, h = i & 3;
        float s = 0.f;
        for (int c = 0; c < 256; ++c) s += W1[k * 1024 + h * 256 + c] * as1[h * 256 + c];
        fold[64 + i] = s;
    } else if (t >= 320 && t < 540) {
        int i = t - 320, k = i >> 2, h = i & 3;
        float s = 0.f;
        for (int c = 0; c < 256; ++c) s += W1[k * 1024 + h * 256 + c] * ad1[h * 256 + c];
        fold[320 + i] = s;
    }
}

// --- merged x prep: fragment-order cast + folded ss1/sd1 --------------------
__global__ void k_prep_x(const float* __restrict__ x, const float* __restrict__ wa1,
                         const float* __restrict__ wd1, _Float16* __restrict__ xbf,
                         float* __restrict__ ss1, float* __restrict__ sd1, int N) {
    int idx = blockIdx.x * blockDim.x + threadIdx.x;
    if (idx < N * 64) {
        int n = idx >> 6, k = idx & 63;
        _Float16 v = (k < 55) ? (_Float16)x[(size_t)n * 55 + k] : (_Float16)0.f;
        int g = n >> 6, nl = n & 63;
        size_t dst = (size_t)g * 4096 +
                     (((k >> 4) * 2 + (nl >> 5)) * 512 +
                      ((k & 15) + 16 * ((nl >> 3) & 3)) * 8 + (nl & 7));
        xbf[dst] = v;
        return;
    }
    int n = idx - N * 64;
    if (n >= N) return;
    float a0 = 0, a1 = 0, a2 = 0, a3 = 0, d0 = 0, d1 = 0, d2 = 0, d3 = 0;
    for (int k = 0; k < 55; ++k) {
        float xv = x[(size_t)n * 55 + k];
        float4 wa = *reinterpret_cast<const float4*>(&wa1[k * 4]);
        float4 wd = *reinterpret_cast<const float4*>(&wd1[k * 4]);
        a0 += xv * wa.x; a1 += xv * wa.y; a2 += xv * wa.z; a3 += xv * wa.w;
        d0 += xv * wd.x; d1 += xv * wd.y; d2 += xv * wd.z; d3 += xv * wd.w;
    }
    *reinterpret_cast<float4*>(&ss1[n * 4]) = make_float4(a0, a1, a2, a3);
    *reinterpret_cast<float4*>(&sd1[n * 4]) = make_float4(d0, d1, d2, d3);
}

// --- per-graph CSR + edge-attr dots, all in LDS ------------------------------
__global__ __launch_bounds__(256) void k_graph_csr(
    const int* __restrict__ ei, const float* __restrict__ ea,
    const float* __restrict__ we1, const float* __restrict__ we2,
    int* __restrict__ coff, int* __restrict__ eid,
    float* __restrict__ ead1, float* __restrict__ ead2, int E, int B) {
    __shared__ int degL[64];
    __shared__ float meaL[64][6];
    __shared__ int cs[65];
    __shared__ int fillL[64];
    int g = blockIdx.x;
    int ng = g * 64;
    int e0 = g * 256;
    int tid = threadIdx.x;
    if (tid < 64) {
        degL[tid] = 0; fillL[tid] = 0;
#pragma unroll
        for (int k = 0; k < 6; ++k) meaL[tid][k] = 0.f;
    }
    __syncthreads();
    int eg = e0 + tid;
    int dst = ei[E + eg];
    int dl = dst - ng;
    atomicAdd(&degL[dl], 1);
#pragma unroll
    for (int k = 0; k < 6; ++k) atomicAdd(&meaL[dl][k], ea[(size_t)eg * 6 + k]);
    __syncthreads();
    if (tid < 64) {
        int v = degL[tid] + 1;
        int incl = v;
#pragma unroll
        for (int o = 1; o < 64; o <<= 1) {
            int up = __shfl_up(incl, o);
            if (tid >= o) incl += up;
        }
        cs[tid + 1] = incl;
        if (tid == 0) cs[0] = 0;
        coff[ng + tid] = g * 320 + (incl - v);
        if (g == B - 1 && tid == 63) coff[ng + 64] = (g + 1) * 320;
    }
    __syncthreads();
    {
        float v[4] = {};
        float v2 = 0.f;
        const float* eap = ea + (size_t)eg * 6;
#pragma unroll
        for (int k = 0; k < 6; ++k) {
            float a = eap[k];
#pragma unroll
            for (int h = 0; h < 4; ++h) v[h] += a * we1[k * 4 + h];
            v2 += a * we2[k];
        }
#pragma unroll
        for (int h = 0; h < 4; ++h) ead1[(size_t)eg * 4 + h] = v[h];
        ead2[eg] = v2;
        int pos = cs[dl] + atomicAdd(&fillL[dl], 1);
        eid[g * 320 + pos] = eg;
    }
    if (tid < 64) {
        float inv = 1.f / fmaxf((float)degL[tid], 1.f);
        float v[4] = {};
        float v2 = 0.f;
#pragma unroll
        for (int k = 0; k < 6; ++k) {
            float a = meaL[tid][k] * inv;
#pragma unroll
            for (int h = 0; h < 4; ++h) v[h] += a * we1[k * 4 + h];
            v2 += a * we2[k];
        }
        int se = E + ng + tid;
#pragma unroll
        for (int h = 0; h < 4; ++h) ead1[(size_t)se * 4 + h] = v[h];
        ead2[se] = v2;
        int pos = cs[tid] + atomicAdd(&fillL[tid], 1);
        eid[g * 320 + pos] = se;
    }
}

__global__ __launch_bounds__(512) void k_pbuild1(
    const _Float16* __restrict__ xbf,
    const int* __restrict__ coff, const int* __restrict__ eid, const int* __restrict__ ei,
    const float* __restrict__ ead1, const float* __restrict__ ss1,
    const float* __restrict__ sd1,
    _Float16* __restrict__ XA, int ldxa, int E, int g0) {
    __shared__ _Float16 Pm[4][64 * 64];
    __shared__ float llds[384][4];
    __shared__ int slds[384];
    int g = blockIdx.x;
    int ng = (g0 + g) * 64;
    int lr0 = g * 64;
    int tid = threadIdx.x;
    int lane = tid & 63, wid = tid >> 6;
    int l15 = lane & 15, l4 = lane >> 4;
    for (int i = tid; i < 4 * 64 * 64 / 8; i += 512)
        *reinterpret_cast<int4*>(&Pm[0][0] + i * 8) = int4{0, 0, 0, 0};
    int pbase = coff[ng];
    int pcnt = coff[ng + 64] - pbase;
    if (pcnt > 384) pcnt = 384;
    for (int p = tid; p < pcnt; p += 512) {
        int e = eid[pbase + p];
        int s, d;
        if (e < E) { s = ei[e]; d = ei[E + e]; } else { s = e - E; d = s; }
        slds[p] = s - ng;
        float4 sv = *reinterpret_cast<const float4*>(&ss1[s * 4]);
        float4 dv = *reinterpret_cast<const float4*>(&sd1[d * 4]);
        float4 ev = *reinterpret_cast<const float4*>(&ead1[(size_t)e * 4]);
        float v0 = sv.x + dv.x + ev.x, v1 = sv.y + dv.y + ev.y;
        float v2 = sv.z + dv.z + ev.z, v3 = sv.w + dv.w + ev.w;
        llds[p][0] = (v0 > 0.f) ? v0 : LEAKY_SLOPE * v0;
        llds[p][1] = (v1 > 0.f) ? v1 : LEAKY_SLOPE * v1;
        llds[p][2] = (v2 > 0.f) ? v2 : LEAKY_SLOPE * v2;
        llds[p][3] = (v3 > 0.f) ? v3 : LEAKY_SLOPE * v3;
    }
    __syncthreads();
    if (tid < 256) {
        int dst = tid >> 2, h = tid & 3;
        int p0 = coff[ng + dst] - pbase, p1 = coff[ng + dst + 1] - pbase;
        float m = -1e30f;
        for (int p = p0; p < p1; ++p) m = fmaxf(m, llds[p][h]);
        float sm = 0.f;
        for (int p = p0; p < p1; ++p) sm += expf(llds[p][h] - m);
        float iv = 1.f / (sm + 1e-16f);
        for (int p = p0; p < p1; ++p) {
            int src = slds[p];
            int pos = dst * 64 + (((src >> 3) ^ (dst & 7)) << 3) + (src & 7);
            Pm[h][pos] = (_Float16)((float)Pm[h][pos] + expf(llds[p][h] - m) * iv);
        }
    }
    __syncthreads();
    int head = wid >> 1, fjh = wid & 1;
    const _Float16* xg = xbf + (size_t)(g0 + g) * 4096;
    facc4 acc[4][2] = {};
#pragma unroll
    for (int kk = 0; kk < 2; ++kk) {
        half8 af[4], bf[2];
#pragma unroll
        for (int f = 0; f < 4; ++f) {
            int arow = f * 16 + l15;
            af[f] = *reinterpret_cast<const half8*>(
                &Pm[head][arow * 64 + (((kk * 4 + l4) ^ (arow & 7)) << 3)]);
        }
#pragma unroll
        for (int f = 0; f < 2; ++f)
            bf[f] = *reinterpret_cast<const half8*>(
                xg + (((fjh * 2 + f) * 2 + kk) * 512 + lane * 8));
#pragma unroll
        for (int fi = 0; fi < 4; ++fi)
#pragma unroll
            for (int fj = 0; fj < 2; ++fj)
                acc[fi][fj] = __builtin_amdgcn_mfma_f32_16x16x32_f16(
                    af[fi], bf[fj], acc[fi][fj], 0, 0, 0);
    }
#pragma unroll
    for (int fi = 0; fi < 4; ++fi)
#pragma unroll
        for (int fj = 0; fj < 2; ++fj)
#pragma unroll
            for (int i = 0; i < 4; ++i) {
                int r = fi * 16 + l4 * 4 + i;
                int k2 = fjh * 32 + fj * 16 + l15;
                XA[((size_t)head * ldxa + lr0 + r) * 64 + k2] = (_Float16)acc[fi][fj][i];
            }
}

__global__ __launch_bounds__(256) void k_gemm_heads(
    const _Float16* __restrict__ XA, int ldxa, const _Float16* __restrict__ w1t,
    _Float16* __restrict__ hpre) {
    int h = blockIdx.z;
    const _Float16* A = XA + (size_t)h * ldxa * 64;
    const _Float16* BT = w1t + (size_t)h * 256 * 64;
    __shared__ _Float16 As[128 * 64];
    __shared__ _Float16 Bs[128 * 64];
    int tid = threadIdx.x;
    int lane = tid & 63, wid = tid >> 6;
    int wr = wid >> 1, wc = wid & 1;
    int l15 = lane & 15, l4 = lane >> 4;
    int r0 = blockIdx.y * 128, c0 = blockIdx.x * 128;
    facc4 acc[4][4] = {};
#pragma unroll
    for (int i = 0; i < 4; ++i) {
        int ch = tid + 256 * i;
        int row = ch >> 3, col16 = ch & 7;
        int sw = col16 ^ (row & 7);
        *reinterpret_cast<int4*>(&As[row * 64 + sw * 8]) =
            *reinterpret_cast<const int4*>(A + (size_t)(r0 + row) * 64 + col16 * 8);
        *reinterpret_cast<int4*>(&Bs[row * 64 + sw * 8]) =
            *reinterpret_cast<const int4*>(BT + (size_t)(c0 + row) * 64 + col16 * 8);
    }
    __syncthreads();
#pragma unroll
    for (int kk = 0; kk < 2; ++kk) {
        half8 af[4], bf[4];
#pragma unroll
        for (int f = 0; f < 4; ++f) {
            int arow = wr * 64 + f * 16 + l15;
            int ac = (kk * 4 + l4) ^ (arow & 7);
            af[f] = *reinterpret_cast<const half8*>(&As[arow * 64 + ac * 8]);
            int brow = wc * 64 + f * 16 + l15;
            int bc = (kk * 4 + l4) ^ (brow & 7);
            bf[f] = *reinterpret_cast<const half8*>(&Bs[brow * 64 + bc * 8]);
        }
#pragma unroll
        for (int fi = 0; fi < 4; ++fi)
#pragma unroll
            for (int fj = 0; fj < 4; ++fj)
                acc[fi][fj] = __builtin_amdgcn_mfma_f32_16x16x32_f16(
                    af[fi], bf[fj], acc[fi][fj], 0, 0, 0);
    }
#pragma unroll
    for (int fi = 0; fi < 4; ++fi)
#pragma unroll
        for (int fj = 0; fj < 4; ++fj)
#pragma unroll
            for (int i = 0; i < 4; ++i) {
                int r = r0 + wr * 64 + fi * 16 + l4 * 4 + i;
                int cc = h * 256 + c0 + wc * 64 + fj * 16 + l15;
                hpre[(size_t)r * 1024 + cc] = (_Float16)acc[fi][fj][i];
            }
}

// --- pure streaming LN + ReLU -----------------------------------------------
__global__ __launch_bounds__(256) void k_ln1(
    const _Float16* __restrict__ hpre, const float* __restrict__ b1,
    const float* __restrict__ g1, const float* __restrict__ be1,
    _Float16* __restrict__ hln) {
    int row = blockIdx.x * 4 + (threadIdx.x >> 6);
    int lane = threadIdx.x & 63;
    const _Float16* src = hpre + (size_t)row * 1024;
    float v[16];
    half8 h0 = *reinterpret_cast<const half8*>(src + lane * 8);
    half8 h1 = *reinterpret_cast<const half8*>(src + 512 + lane * 8);
    float lsum = 0.f, lsq = 0.f;
#pragma unroll
    for (int j = 0; j < 8; ++j) {
        v[j] = (float)h0[j] + b1[lane * 8 + j];
        v[8 + j] = (float)h1[j] + b1[512 + lane * 8 + j];
    }
#pragma unroll
    for (int j = 0; j < 16; ++j) { lsum += v[j]; lsq += v[j] * v[j]; }
    for (int o = 32; o; o >>= 1) { lsum += __shfl_xor(lsum, o); lsq += __shfl_xor(lsq, o); }
    float mu = lsum * (1.f / 1024.f);
    float var = lsq * (1.f / 1024.f) - mu * mu;
    float rstd = rsqrtf(var + 1e-5f);
    half8 o0, o1;
#pragma unroll
    for (int j = 0; j < 8; ++j) {
        int c = lane * 8 + j;
        o0[j] = (_Float16)fmaxf((v[j] - mu) * rstd * g1[c] + be1[c], 0.f);
    }
#pragma unroll
    for (int j = 0; j < 8; ++j) {
        int c = 512 + lane * 8 + j;
        o1[j] = (_Float16)fmaxf((v[8 + j] - mu) * rstd * g1[c] + be1[c], 0.f);
    }
    *reinterpret_cast<half8*>(hln + (size_t)row * 1024 + lane * 8) = o0;
    *reinterpret_cast<half8*>(hln + (size_t)row * 1024 + 512 + lane * 8) = o1;
}

// --- GEMM2: h2f(frag-order) = hln[NC,1024] @ w2t[256,1024]^T; A read once ----
__global__ __launch_bounds__(512) void k_gemm2(
    const _Float16* __restrict__ A, const _Float16* __restrict__ BT,
    _Float16* __restrict__ h2f) {
    __shared__ _Float16 As[128 * 64];
    __shared__ _Float16 Bs[256 * 64];
    int tid = threadIdx.x;
    int lane = tid & 63, wid = tid >> 6;
    int wr = wid >> 2, wc = wid & 3;
    int l15 = lane & 15, l4 = lane >> 4;
    int r0 = blockIdx.x * 128;
    facc4 acc[4][4] = {};
    for (int kt = 0; kt < 1024; kt += 64) {
#pragma unroll
        for (int i = 0; i < 2; ++i) {
            int ch = tid + 512 * i;
            int row = ch >> 3, col16 = ch & 7;
            int sw = col16 ^ (row & 7);
            *reinterpret_cast<int4*>(&As[row * 64 + sw * 8]) =
                *reinterpret_cast<const int4*>(A + (size_t)(r0 + row) * 1024 + kt + col16 * 8);
        }
#pragma unroll
        for (int i = 0; i < 4; ++i) {
            int ch = tid + 512 * i;
            int row = ch >> 3, col16 = ch & 7;
            int sw = col16 ^ (row & 7);
            *reinterpret_cast<int4*>(&Bs[row * 64 + sw * 8]) =
                *reinterpret_cast<const int4*>(BT + (size_t)row * 1024 + kt + col16 * 8);
        }
        __syncthreads();
#pragma unroll
        for (int kk = 0; kk < 2; ++kk) {
            half8 af[4], bf[4];
#pragma unroll
            for (int f = 0; f < 4; ++f) {
                int arow = wr * 64 + f * 16 + l15;
                int ac = (kk * 4 + l4) ^ (arow & 7);
                af[f] = *reinterpret_cast<const half8*>(&As[arow * 64 + ac * 8]);
                int brow = wc * 64 + f * 16 + l15;
                int bc = (kk * 4 + l4) ^ (brow & 7);
                bf[f] = *reinterpret_cast<const half8*>(&Bs[brow * 64 + bc * 8]);
            }
#pragma unroll
            for (int fi = 0; fi < 4; ++fi)
#pragma unroll
                for (int fj = 0; fj < 4; ++fj)
                    acc[fi][fj] = __builtin_amdgcn_mfma_f32_16x16x32_f16(
                        af[fi], bf[fj], acc[fi][fj], 0, 0, 0);
        }
        __syncthreads();
    }
#pragma unroll
    for (int fi = 0; fi < 4; ++fi)
#pragma unroll
        for (int fj = 0; fj < 4; ++fj)
#pragma unroll
            for (int i = 0; i < 4; ++i) {
                int r = r0 + wr * 64 + fi * 16 + l4 * 4 + i;
                int cc = wc * 64 + fj * 16 + l15;
                int g = r >> 6, nl = r & 63;
                size_t dst = (size_t)g * 16384 +
                             (((cc >> 4) * 2 + (nl >> 5)) * 512 +
                              ((cc & 15) + 16 * ((nl >> 3) & 3)) * 8 + (nl & 7));
                h2f[dst] = (_Float16)acc[fi][fj][i];
            }
}

// --- merged layer-2 + scores + softmax + pool + emb (per graph) --------------
__global__ __launch_bounds__(512) void k_graph2f(
    const _Float16* __restrict__ h2f,
    const int* __restrict__ coff, const int* __restrict__ eid, const int* __restrict__ ei,
    const float* __restrict__ ead2, const float* __restrict__ as2,
    const float* __restrict__ ad2,
    const float* __restrict__ b2, const float* __restrict__ g2,
    const float* __restrict__ be2,
    const _Float16* __restrict__ wat, const float* __restrict__ va,
    const int* __restrict__ food, const float* __restrict__ emb,
    float* __restrict__ out, int E, int B, int g0) {
    __shared__ _Float16 hfL[64 * 256];       // 32 KB arena (aliases Pm/llds/slds)
    _Float16* Pm = hfL;                      // [0, 8192) bytes
    float* llds = reinterpret_cast<float*>(hfL + 4096);        // 1536 B
    int* slds = reinterpret_cast<int*>(hfL + 4096 + 768);      // 1536 B
    __shared__ float rsum[64], rsq[64], ss2L[64], sd2L[64];
    __shared__ float part[8][64];
    __shared__ float at[64];
    int g = blockIdx.x;
    int b = g0 + g;
    int ng = (g0 + g) * 64;
    int tid = threadIdx.x;
    int lane = tid & 63, wid = tid >> 6;
    int l15 = lane & 15, l4 = lane >> 4;
    int cbase = wid * 32;
    if (tid < 64) { rsum[tid] = 0.f; rsq[tid] = 0.f; ss2L[tid] = 0.f; sd2L[tid] = 0.f; }
    for (int i = tid; i < 64 * 64 / 8; i += 512)
        *reinterpret_cast<int4*>(&Pm[0] + i * 8) = int4{0, 0, 0, 0};
    __syncthreads();
    const _Float16* hg = h2f + (size_t)g * 16384;
    half8 bfr[2][2];
#pragma unroll
    for (int kk = 0; kk < 2; ++kk)
#pragma unroll
        for (int f = 0; f < 2; ++f)
            bfr[kk][f] = *reinterpret_cast<const half8*>(
                hg + ((((cbase + f * 16) >> 4) * 2 + kk) * 512 + lane * 8));
    float ps[2][8] = {}, pd[2][8] = {};
#pragma unroll
    for (int kk = 0; kk < 2; ++kk)
#pragma unroll
        for (int f = 0; f < 2; ++f) {
            int c = cbase + f * 16 + l15;
            float a2 = as2[c], d2 = ad2[c];
#pragma unroll
            for (int j = 0; j < 8; ++j) {
                float hv = (float)bfr[kk][f][j];
                ps[kk][j] += hv * a2;
                pd[kk][j] += hv * d2;
            }
        }
#pragma unroll
    for (int kk = 0; kk < 2; ++kk)
#pragma unroll
        for (int j = 0; j < 8; ++j) {
            float s = ps[kk][j], d = pd[kk][j];
            s += __shfl_xor(s, 1); d += __shfl_xor(d, 1);
            s += __shfl_xor(s, 2); d += __shfl_xor(d, 2);
            s += __shfl_xor(s, 4); d += __shfl_xor(d, 4);
            s += __shfl_xor(s, 8); d += __shfl_xor(d, 8);
            if (l15 == 0) {
                int n = kk * 32 + l4 * 8 + j;
                atomicAdd(&ss2L[n], s);
                atomicAdd(&sd2L[n], d);
            }
        }
    __syncthreads();
    int pbase = coff[ng];
    int pcnt = coff[ng + 64] - pbase;
    if (pcnt > 384) pcnt = 384;
    for (int p = tid; p < pcnt; p += 512) {
        int e = eid[pbase + p];
        int s, d;
        if (e < E) { s = ei[e]; d = ei[E + e]; } else { s = e - E; d = s; }
        slds[p] = s - ng;
        float v = ss2L[s - ng] + sd2L[d - ng] + ead2[e];
        llds[p] = (v > 0.f) ? v : LEAKY_SLOPE * v;
    }
    __syncthreads();
    if (tid < 64) {
        int dst = tid;
        int p0 = coff[ng + dst] - pbase, p1 = coff[ng + dst + 1] - pbase;
        float m = -1e30f;
        for (int p = p0; p < p1; ++p) m = fmaxf(m, llds[p]);
        float sm = 0.f;
        for (int p = p0; p < p1; ++p) sm += expf(llds[p] - m);
        float iv = 1.f / (sm + 1e-16f);
        for (int p = p0; p < p1; ++p) {
            int src = slds[p];
            int pos = dst * 64 + (((src >> 3) ^ (dst & 7)) << 3) + (src & 7);
            Pm[pos] = (_Float16)((float)Pm[pos] + expf(llds[p] - m) * iv);
        }
    }
    __syncthreads();
    // MFMA: hf[dst][c] = P @ h2
    facc4 acc[4][2] = {};
#pragma unroll
    for (int kk = 0; kk < 2; ++kk) {
        half8 af[4];
#pragma unroll
        for (int f = 0; f < 4; ++f) {
            int arow = f * 16 + l15;
            af[f] = *reinterpret_cast<const half8*>(
                &Pm[arow * 64 + (((kk * 4 + l4) ^ (arow & 7)) << 3)]);
        }
#pragma unroll
        for (int fi = 0; fi < 4; ++fi)
#pragma unroll
            for (int fj = 0; fj < 2; ++fj)
                acc[fi][fj] = __builtin_amdgcn_mfma_f32_16x16x32_f16(
                    af[fi], bfr[kk][fj], acc[fi][fj], 0, 0, 0);
    }
    float bb[2];
#pragma unroll
    for (int fj = 0; fj < 2; ++fj) bb[fj] = b2[cbase + fj * 16 + l15];
#pragma unroll
    for (int fi = 0; fi < 4; ++fi)
#pragma unroll
        for (int i = 0; i < 4; ++i) {
            float s = 0.f, q = 0.f;
#pragma unroll
            for (int fj = 0; fj < 2; ++fj) {
                float v = acc[fi][fj][i] + bb[fj];
                acc[fi][fj][i] = v;
                s += v; q += v * v;
            }
            s += __shfl_xor(s, 1); q += __shfl_xor(q, 1);
            s += __shfl_xor(s, 2); q += __shfl_xor(q, 2);
            s += __shfl_xor(s, 4); q += __shfl_xor(q, 4);
            s += __shfl_xor(s, 8); q += __shfl_xor(q, 8);
            if (l15 == 0) {
                int r = fi * 16 + l4 * 4 + i;
                atomicAdd(&rsum[r], s);
                atomicAdd(&rsq[r], q);
            }
        }
    __syncthreads();    // also orders: Pm/llds/slds reads done before hfL writes
    // LN apply: keep f32 in acc; write f16 to hfL in scores-fragment order
#pragma unroll
    for (int fi = 0; fi < 4; ++fi)
#pragma unroll
        for (int i = 0; i < 4; ++i) {
            int rl = l4 * 4 + i;                 // row & 15
            float mu = rsum[fi * 16 + rl] * (1.f / 256.f);
            float var = rsq[fi * 16 + rl] * (1.f / 256.f) - mu * mu;
            float rstd = rsqrtf(var + 1e-5f);
#pragma unroll
            for (int fj = 0; fj < 2; ++fj) {
                int c = cbase + fj * 16 + l15;
                float v = (acc[fi][fj][i] - mu) * rstd * g2[c] + be2[c];
                acc[fi][fj][i] = v;              // keep f32 for pooling
                int idx = (fi * 8 + wid) * 512 +
                          ((fj * 2 + (l15 >> 3)) * 16 + rl) * 8 + (l15 & 7);
                hfL[idx] = (_Float16)v;
            }
        }
    __syncthreads();
    // scores GEMM: hfL(LDS fragments) @ wat^T
    facc4 acc2[4][2] = {};
#pragma unroll
    for (int kk = 0; kk < 8; ++kk) {
        half8 af[4], bf[2];
#pragma unroll
        for (int f = 0; f < 4; ++f)
            af[f] = *reinterpret_cast<const half8*>(&hfL[(f * 8 + kk) * 512 + lane * 8]);
#pragma unroll
        for (int f = 0; f < 2; ++f)
            bf[f] = *reinterpret_cast<const half8*>(
                wat + (((wid * 2 + f) * 8 + kk) * 512 + lane * 8));
#pragma unroll
        for (int fi = 0; fi < 4; ++fi)
#pragma unroll
            for (int fj = 0; fj < 2; ++fj)
                acc2[fi][fj] = __builtin_amdgcn_mfma_f32_16x16x32_f16(
                    af[fi], bf[fj], acc2[fi][fj], 0, 0, 0);
    }
    float vac[2];
#pragma unroll
    for (int fj = 0; fj < 2; ++fj) vac[fj] = va[cbase + fj * 16 + l15];
#pragma unroll
    for (int fi = 0; fi < 4; ++fi)
#pragma unroll
        for (int i = 0; i < 4; ++i) {
            float v = tanhf(acc2[fi][0][i]) * vac[0] + tanhf(acc2[fi][1][i]) * vac[1];
            v += __shfl_xor(v, 1); v += __shfl_xor(v, 2);
            v += __shfl_xor(v, 4); v += __shfl_xor(v, 8);
            if (l15 == 0) part[wid][fi * 16 + l4 * 4 + i] = v;
        }
    __syncthreads();
    if (tid < 64) {
        float sc = part[0][tid] + part[1][tid] + part[2][tid] + part[3][tid] +
                   part[4][tid] + part[5][tid] + part[6][tid] + part[7][tid];
        float m = sc;
        for (int o = 32; o; o >>= 1) m = fmaxf(m, __shfl_xor(m, o));
        float ex = expf(sc - m);
        float s = ex;
        for (int o = 32; o; o >>= 1) s += __shfl_xor(s, o);
        float a = ex / (s + 1e-16f);
        at[tid] = a;
        out[(size_t)B * 512 + (size_t)b * 64 + tid] = a;      // attn
    }
    __syncthreads();
    // pool from live f32 acc: per channel max over rows of hf*at
#pragma unroll
    for (int fj = 0; fj < 2; ++fj) {
        float m = -1e30f;
#pragma unroll
        for (int fi = 0; fi < 4; ++fi)
#pragma unroll
            for (int i = 0; i < 4; ++i) {
                int r = fi * 16 + l4 * 4 + i;
                m = fmaxf(m, acc[fi][fj][i] * at[r]);
            }
        m = fmaxf(m, __shfl_xor(m, 16));
        m = fmaxf(m, __shfl_xor(m, 32));
        if (l4 == 0)
            out[(size_t)b * 256 + cbase + fj * 16 + l15] = m;  // drug_fea
    }
    if (tid < 256)
        out[(size_t)B * 256 + (size_t)b * 256 + tid] =
            emb[(size_t)food[b] * 256 + tid];                  // food_fea
}

// ---------------------------------------------------------------------------
extern "C" void kernel_launch(void* const* d_in, const int* in_sizes, int n_in,
                              void* d_out, int out_size, void* d_ws, size_t ws_size,
                              hipStream_t stream) {
    const float* x   = (const float*)d_in[0];
    const float* ea  = (const float*)d_in[1];
    const int*   ei  = (const int*)d_in[2];
    const int*   food= (const int*)d_in[4];
    const float* W1  = (const float*)d_in[5];
    const float* as1 = (const float*)d_in[6];
    const float* ad1 = (const float*)d_in[7];
    const float* We1 = (const float*)d_in[8];
    const float* ae1 = (const float*)d_in[9];
    const float* b1  = (const float*)d_in[10];
    const float* g1  = (const float*)d_in[11];
    const float* be1 = (const float*)d_in[12];
    const float* W2  = (const float*)d_in[13];
    const float* as2 = (const float*)d_in[14];
    const float* ad2 = (const float*)d_in[15];
    const float* We2 = (const float*)d_in[16];
    const float* ae2 = (const float*)d_in[17];
    const float* b2  = (const float*)d_in[18];
    const float* g2  = (const float*)d_in[19];
    const float* be2 = (const float*)d_in[20];
    const float* Wa  = (const float*)d_in[21];
    const float* va  = (const float*)d_in[22];
    const float* emb = (const float*)d_in[23];
    float* out = (float*)d_out;

    const int N  = in_sizes[0] / 55;
    const int E  = in_sizes[2] / 2;
    const int B  = in_sizes[4];
    const int Ef = E + N;
    const int LPG = N / B;

    char* w = (char*)d_ws;
    size_t off = 0;
    auto take = [&](size_t bytes) -> char* {
        char* p = w + off;
        off = (off + bytes + 255) & ~(size_t)255;
        return p;
    };
    int*      coff = (int*)take((size_t)(N + 1) * 4);
    int*      eid  = (int*)take((size_t)Ef * 4);
    float*    ead1 = (float*)take((size_t)Ef * 4 * 4);
    float*    ead2 = (float*)take((size_t)Ef * 4);
    float*    fold = (float*)take(4096 * 4);
    float*    ss1  = (float*)take((size_t)N * 4 * 4);
    float*    sd1  = (float*)take((size_t)N * 4 * 4);
    _Float16* xbf  = (_Float16*)take((size_t)N * 64 * 2);
    _Float16* w1t  = (_Float16*)take((size_t)1024 * 64 * 2);
    _Float16* w2t  = (_Float16*)take((size_t)256 * 1024 * 2);
    _Float16* wat  = (_Float16*)take((size_t)256 * 256 * 2);
    size_t smallEnd = off;

    int G = B;
    while (G > 2 && smallEnd + (size_t)G * 32768 + 2ull * G * 131072 + 768 > ws_size) G >>= 1;
    _Float16* XA   = (_Float16*)take((size_t)G * 32768);
    _Float16* hpre = (_Float16*)take((size_t)G * 131072);
    _Float16* hln  = (_Float16*)take((size_t)G * 131072);
    _Float16* h2f  = (_Float16*)hpre;       // overlay: hpre dead after k_ln1

    k_prep_w<<<(1024 * 64 + 256 * 1024 + 256 * 256 + 3072 + 255) / 256, 256, 0, stream>>>(
        W1, W2, Wa, We1, ae1, We2, ae2, as1, ad1, w1t, w2t, wat, fold);
    k_prep_x<<<(N * 64 + N + 255) / 256, 256, 0, stream>>>(
        x, fold + 64, fold + 320, xbf, ss1, sd1, N);
    k_graph_csr<<<B, 256, 0, stream>>>(ei, ea, fold, fold + 32, coff, eid,
                                       ead1, ead2, E, B);

    for (int g0 = 0; g0 < B; g0 += G) {
        int Gc = (g0 + G <= B) ? G : (B - g0);
        int NC = Gc * LPG;
        k_pbuild1<<<Gc, 512, 0, stream>>>(xbf, coff, eid, ei, ead1, ss1, sd1,
                                          XA, NC, E, g0);
        k_gemm_heads<<<dim3(2, NC / 128, 4), 256, 0, stream>>>(XA, NC, w1t, hpre);
        k_ln1<<<NC / 4, 256, 0, stream>>>(hpre, b1, g1, be1, hln);
        k_gemm2<<<NC / 128, 512, 0, stream>>>(hln, w2t, h2f);
        k_graph2f<<<Gc, 512, 0, stream>>>(h2f, coff, eid, ei, ead2, as2, ad2,
                                          b2, g2, be2, wat, va, food, emb,
                                          out, E, B, g0);
    }
}

// Round 18
// 148.065 us; speedup vs baseline: 1.0447x; 1.0211x over previous
//
#include <hip/hip_runtime.h>
#include <cstdint>
#include <cstddef>

// ---------------------------------------------------------------------------
// GATExtractPart round 18 (base: round 17 = round 14 config, 150-151us):
//  - k_layer1 = k_pbuild1 + k_gemm_heads merged: XA kept in a 32KB LDS
//    fragment arena (aliases dead Pm), per-graph XA@W1 GEMM with
//    fragment-order w1f weights loaded direct from L2. -1 launch/drain,
//    XA global round-trip removed. ln1/gemm2/graph2f unchanged.
// ---------------------------------------------------------------------------

#define LEAKY_SLOPE 0.2f

typedef __attribute__((ext_vector_type(8))) _Float16 half8;
typedef __attribute__((ext_vector_type(4))) float facc4;

// --- merged weight prep ------------------------------------------------------
// w1f: per-head fragment order: head*16384 + ((c>>4)*2+(k>>5))*512 +
//      ((c&15)+16*((k>>3)&3))*8 + (k&7)
__global__ void k_prep_w(const float* __restrict__ W1, const float* __restrict__ W2,
                         const float* __restrict__ Wa,
                         const float* __restrict__ We1, const float* __restrict__ ae1,
                         const float* __restrict__ We2, const float* __restrict__ ae2,
                         const float* __restrict__ as1, const float* __restrict__ ad1,
                         _Float16* __restrict__ w1f, _Float16* __restrict__ w2t,
                         _Float16* __restrict__ wat, float* __restrict__ fold) {
    int idx = blockIdx.x * blockDim.x + threadIdx.x;
    if (idx < 1024 * 64) {
        int head = idx >> 14;
        int rem = idx & 16383;
        int c = rem >> 6, k = rem & 63;
        _Float16 v = (k < 55) ? (_Float16)W1[(size_t)k * 1024 + head * 256 + c]
                              : (_Float16)0.f;
        int dst = head * 16384 + ((c >> 4) * 2 + (k >> 5)) * 512 +
                  ((c & 15) + 16 * ((k >> 3) & 3)) * 8 + (k & 7);
        w1f[dst] = v;
        return;
    }
    idx -= 1024 * 64;
    if (idx < 256 * 1024) {
        int c = idx >> 10, k = idx & 1023;
        w2t[idx] = (_Float16)W2[(size_t)k * 256 + c];
        return;
    }
    idx -= 256 * 1024;
    if (idx < 256 * 256) {
        int c = idx >> 8, k = idx & 255;
        int dst = ((c >> 4) * 8 + (k >> 5)) * 512 + ((c & 15) + 16 * ((k >> 3) & 3)) * 8 + (k & 7);
        wat[dst] = (_Float16)Wa[(size_t)k * 256 + c];
        return;
    }
    int t = idx - 256 * 256;
    if (t < 24) {
        int k = t >> 2, h = t & 3;
        float s = 0.f;
        for (int c = 0; c < 256; ++c) s += We1[k * 1024 + h * 256 + c] * ae1[h * 256 + c];
        fold[t] = s;
    } else if (t < 30) {
        int k = t - 24;
        float s = 0.f;
        for (int c = 0; c < 256; ++c) s += We2[k * 256 + c] * ae2[c];
        fold[32 + k] = s;
    } else if (t >= 64 && t < 284) {
        int i = t - 64, k = i >> 2, h = i & 3;
        float s = 0.f;
        for (int c = 0; c < 256; ++c) s += W1[k * 1024 + h * 256 + c] * as1[h * 256 + c];
        fold[64 + i] = s;
    } else if (t >= 320 && t < 540) {
        int i = t - 320, k = i >> 2, h = i & 3;
        float s = 0.f;
        for (int c = 0; c < 256; ++c) s += W1[k * 1024 + h * 256 + c] * ad1[h * 256 + c];
        fold[320 + i] = s;
    }
}

// --- merged x prep: fragment-order cast + folded ss1/sd1 --------------------
__global__ void k_prep_x(const float* __restrict__ x, const float* __restrict__ wa1,
                         const float* __restrict__ wd1, _Float16* __restrict__ xbf,
                         float* __restrict__ ss1, float* __restrict__ sd1, int N) {
    int idx = blockIdx.x * blockDim.x + threadIdx.x;
    if (idx < N * 64) {
        int n = idx >> 6, k = idx & 63;
        _Float16 v = (k < 55) ? (_Float16)x[(size_t)n * 55 + k] : (_Float16)0.f;
        int g = n >> 6, nl = n & 63;
        size_t dst = (size_t)g * 4096 +
                     (((k >> 4) * 2 + (nl >> 5)) * 512 +
                      ((k & 15) + 16 * ((nl >> 3) & 3)) * 8 + (nl & 7));
        xbf[dst] = v;
        return;
    }
    int n = idx - N * 64;
    if (n >= N) return;
    float a0 = 0, a1 = 0, a2 = 0, a3 = 0, d0 = 0, d1 = 0, d2 = 0, d3 = 0;
    for (int k = 0; k < 55; ++k) {
        float xv = x[(size_t)n * 55 + k];
        float4 wa = *reinterpret_cast<const float4*>(&wa1[k * 4]);
        float4 wd = *reinterpret_cast<const float4*>(&wd1[k * 4]);
        a0 += xv * wa.x; a1 += xv * wa.y; a2 += xv * wa.z; a3 += xv * wa.w;
        d0 += xv * wd.x; d1 += xv * wd.y; d2 += xv * wd.z; d3 += xv * wd.w;
    }
    *reinterpret_cast<float4*>(&ss1[n * 4]) = make_float4(a0, a1, a2, a3);
    *reinterpret_cast<float4*>(&sd1[n * 4]) = make_float4(d0, d1, d2, d3);
}

// --- per-graph CSR + edge-attr dots, all in LDS ------------------------------
__global__ __launch_bounds__(256) void k_graph_csr(
    const int* __restrict__ ei, const float* __restrict__ ea,
    const float* __restrict__ we1, const float* __restrict__ we2,
    int* __restrict__ coff, int* __restrict__ eid,
    float* __restrict__ ead1, float* __restrict__ ead2, int E, int B) {
    __shared__ int degL[64];
    __shared__ float meaL[64][6];
    __shared__ int cs[65];
    __shared__ int fillL[64];
    int g = blockIdx.x;
    int ng = g * 64;
    int e0 = g * 256;
    int tid = threadIdx.x;
    if (tid < 64) {
        degL[tid] = 0; fillL[tid] = 0;
#pragma unroll
        for (int k = 0; k < 6; ++k) meaL[tid][k] = 0.f;
    }
    __syncthreads();
    int eg = e0 + tid;
    int dst = ei[E + eg];
    int dl = dst - ng;
    atomicAdd(&degL[dl], 1);
#pragma unroll
    for (int k = 0; k < 6; ++k) atomicAdd(&meaL[dl][k], ea[(size_t)eg * 6 + k]);
    __syncthreads();
    if (tid < 64) {
        int v = degL[tid] + 1;
        int incl = v;
#pragma unroll
        for (int o = 1; o < 64; o <<= 1) {
            int up = __shfl_up(incl, o);
            if (tid >= o) incl += up;
        }
        cs[tid + 1] = incl;
        if (tid == 0) cs[0] = 0;
        coff[ng + tid] = g * 320 + (incl - v);
        if (g == B - 1 && tid == 63) coff[ng + 64] = (g + 1) * 320;
    }
    __syncthreads();
    {
        float v[4] = {};
        float v2 = 0.f;
        const float* eap = ea + (size_t)eg * 6;
#pragma unroll
        for (int k = 0; k < 6; ++k) {
            float a = eap[k];
#pragma unroll
            for (int h = 0; h < 4; ++h) v[h] += a * we1[k * 4 + h];
            v2 += a * we2[k];
        }
#pragma unroll
        for (int h = 0; h < 4; ++h) ead1[(size_t)eg * 4 + h] = v[h];
        ead2[eg] = v2;
        int pos = cs[dl] + atomicAdd(&fillL[dl], 1);
        eid[g * 320 + pos] = eg;
    }
    if (tid < 64) {
        float inv = 1.f / fmaxf((float)degL[tid], 1.f);
        float v[4] = {};
        float v2 = 0.f;
#pragma unroll
        for (int k = 0; k < 6; ++k) {
            float a = meaL[tid][k] * inv;
#pragma unroll
            for (int h = 0; h < 4; ++h) v[h] += a * we1[k * 4 + h];
            v2 += a * we2[k];
        }
        int se = E + ng + tid;
#pragma unroll
        for (int h = 0; h < 4; ++h) ead1[(size_t)se * 4 + h] = v[h];
        ead2[se] = v2;
        int pos = cs[tid] + atomicAdd(&fillL[tid], 1);
        eid[g * 320 + pos] = se;
    }
}

// --- merged layer-1: P build + XA=P@x (LDS) + hpre = XA@W1 -------------------
// 512 threads = 8 waves. Pm (32KB) aliased by XAf after the P@x MFMA.
__global__ __launch_bounds__(512) void k_layer1(
    const _Float16* __restrict__ xbf,
    const int* __restrict__ coff, const int* __restrict__ eid, const int* __restrict__ ei,
    const float* __restrict__ ead1, const float* __restrict__ ss1,
    const float* __restrict__ sd1,
    const _Float16* __restrict__ w1f, _Float16* __restrict__ hpre,
    int E, int g0) {
    __shared__ _Float16 Pm[4][4096];        // 32 KB; XAf aliases after phase 1
    __shared__ float llds[384][4];
    __shared__ int slds[384];
    _Float16* XAf = &Pm[0][0];
    int g = blockIdx.x;
    int ng = (g0 + g) * 64;
    int tid = threadIdx.x;
    int lane = tid & 63, wid = tid >> 6;
    int l15 = lane & 15, l4 = lane >> 4;
    for (int i = tid; i < 4 * 4096 / 8; i += 512)
        *reinterpret_cast<int4*>(&Pm[0][0] + i * 8) = int4{0, 0, 0, 0};
    int pbase = coff[ng];
    int pcnt = coff[ng + 64] - pbase;
    if (pcnt > 384) pcnt = 384;
    for (int p = tid; p < pcnt; p += 512) {
        int e = eid[pbase + p];
        int s, d;
        if (e < E) { s = ei[e]; d = ei[E + e]; } else { s = e - E; d = s; }
        slds[p] = s - ng;
        float4 sv = *reinterpret_cast<const float4*>(&ss1[s * 4]);
        float4 dv = *reinterpret_cast<const float4*>(&sd1[d * 4]);
        float4 ev = *reinterpret_cast<const float4*>(&ead1[(size_t)e * 4]);
        float v0 = sv.x + dv.x + ev.x, v1 = sv.y + dv.y + ev.y;
        float v2 = sv.z + dv.z + ev.z, v3 = sv.w + dv.w + ev.w;
        llds[p][0] = (v0 > 0.f) ? v0 : LEAKY_SLOPE * v0;
        llds[p][1] = (v1 > 0.f) ? v1 : LEAKY_SLOPE * v1;
        llds[p][2] = (v2 > 0.f) ? v2 : LEAKY_SLOPE * v2;
        llds[p][3] = (v3 > 0.f) ? v3 : LEAKY_SLOPE * v3;
    }
    __syncthreads();
    if (tid < 256) {
        int dst = tid >> 2, h = tid & 3;
        int p0 = coff[ng + dst] - pbase, p1 = coff[ng + dst + 1] - pbase;
        float m = -1e30f;
        for (int p = p0; p < p1; ++p) m = fmaxf(m, llds[p][h]);
        float sm = 0.f;
        for (int p = p0; p < p1; ++p) sm += expf(llds[p][h] - m);
        float iv = 1.f / (sm + 1e-16f);
        for (int p = p0; p < p1; ++p) {
            int src = slds[p];
            int pos = dst * 64 + (((src >> 3) ^ (dst & 7)) << 3) + (src & 7);
            Pm[h][pos] = (_Float16)((float)Pm[h][pos] + expf(llds[p][h] - m) * iv);
        }
    }
    __syncthreads();
    // phase 1: XA_h = P_h @ x   (wave: head = wid>>1, k-half fjh = wid&1)
    int head = wid >> 1, fjh = wid & 1;
    const _Float16* xg = xbf + (size_t)(g0 + g) * 4096;
    facc4 acc1[4][2] = {};
#pragma unroll
    for (int kk = 0; kk < 2; ++kk) {
        half8 af[4], bf[2];
#pragma unroll
        for (int f = 0; f < 4; ++f) {
            int arow = f * 16 + l15;
            af[f] = *reinterpret_cast<const half8*>(
                &Pm[head][arow * 64 + (((kk * 4 + l4) ^ (arow & 7)) << 3)]);
        }
#pragma unroll
        for (int f = 0; f < 2; ++f)
            bf[f] = *reinterpret_cast<const half8*>(
                xg + (((fjh * 2 + f) * 2 + kk) * 512 + lane * 8));
#pragma unroll
        for (int fi = 0; fi < 4; ++fi)
#pragma unroll
            for (int fj = 0; fj < 2; ++fj)
                acc1[fi][fj] = __builtin_amdgcn_mfma_f32_16x16x32_f16(
                    af[fi], bf[fj], acc1[fi][fj], 0, 0, 0);
    }
    __syncthreads();          // all Pm reads complete before XAf overwrite
    // write XA into LDS in A-fragment order (over dead Pm region)
#pragma unroll
    for (int fi = 0; fi < 4; ++fi)
#pragma unroll
        for (int fj = 0; fj < 2; ++fj)
#pragma unroll
            for (int i = 0; i < 4; ++i) {
                int rl = l4 * 4 + i;
                int dst = head * 4096 + (fi * 2 + fjh) * 512 +
                          ((fj * 2 + (l15 >> 3)) * 16 + rl) * 8 + (l15 & 7);
                XAf[dst] = (_Float16)acc1[fi][fj][i];
            }
    __syncthreads();
    // phase 2: hpre[:, hw*256+ch*128 .. +128) = XA_hw @ W1_hw
    int hw = wid >> 1, ch = wid & 1;
    facc4 acc2[4][8] = {};
#pragma unroll
    for (int kk = 0; kk < 2; ++kk) {
        half8 af[4], bf[8];
#pragma unroll
        for (int f = 0; f < 4; ++f)
            af[f] = *reinterpret_cast<const half8*>(
                &XAf[hw * 4096 + (f * 2 + kk) * 512 + lane * 8]);
#pragma unroll
        for (int f = 0; f < 8; ++f)
            bf[f] = *reinterpret_cast<const half8*>(
                w1f + hw * 16384 + ((ch * 8 + f) * 2 + kk) * 512 + lane * 8);
#pragma unroll
        for (int fi = 0; fi < 4; ++fi)
#pragma unroll
            for (int fj = 0; fj < 8; ++fj)
                acc2[fi][fj] = __builtin_amdgcn_mfma_f32_16x16x32_f16(
                    af[fi], bf[fj], acc2[fi][fj], 0, 0, 0);
    }
#pragma unroll
    for (int fi = 0; fi < 4; ++fi)
#pragma unroll
        for (int fj = 0; fj < 8; ++fj)
#pragma unroll
            for (int i = 0; i < 4; ++i) {
                int r = g * 64 + fi * 16 + l4 * 4 + i;       // chunk-local node
                int cc = hw * 256 + ch * 128 + fj * 16 + l15;
                hpre[(size_t)r * 1024 + cc] = (_Float16)acc2[fi][fj][i];
            }
}

// --- pure streaming LN + ReLU -----------------------------------------------
__global__ __launch_bounds__(256) void k_ln1(
    const _Float16* __restrict__ hpre, const float* __restrict__ b1,
    const float* __restrict__ g1, const float* __restrict__ be1,
    _Float16* __restrict__ hln) {
    int row = blockIdx.x * 4 + (threadIdx.x >> 6);
    int lane = threadIdx.x & 63;
    const _Float16* src = hpre + (size_t)row * 1024;
    float v[16];
    half8 h0 = *reinterpret_cast<const half8*>(src + lane * 8);
    half8 h1 = *reinterpret_cast<const half8*>(src + 512 + lane * 8);
    float lsum = 0.f, lsq = 0.f;
#pragma unroll
    for (int j = 0; j < 8; ++j) {
        v[j] = (float)h0[j] + b1[lane * 8 + j];
        v[8 + j] = (float)h1[j] + b1[512 + lane * 8 + j];
    }
#pragma unroll
    for (int j = 0; j < 16; ++j) { lsum += v[j]; lsq += v[j] * v[j]; }
    for (int o = 32; o; o >>= 1) { lsum += __shfl_xor(lsum, o); lsq += __shfl_xor(lsq, o); }
    float mu = lsum * (1.f / 1024.f);
    float var = lsq * (1.f / 1024.f) - mu * mu;
    float rstd = rsqrtf(var + 1e-5f);
    half8 o0, o1;
#pragma unroll
    for (int j = 0; j < 8; ++j) {
        int c = lane * 8 + j;
        o0[j] = (_Float16)fmaxf((v[j] - mu) * rstd * g1[c] + be1[c], 0.f);
    }
#pragma unroll
    for (int j = 0; j < 8; ++j) {
        int c = 512 + lane * 8 + j;
        o1[j] = (_Float16)fmaxf((v[8 + j] - mu) * rstd * g1[c] + be1[c], 0.f);
    }
    *reinterpret_cast<half8*>(hln + (size_t)row * 1024 + lane * 8) = o0;
    *reinterpret_cast<half8*>(hln + (size_t)row * 1024 + 512 + lane * 8) = o1;
}

// --- GEMM2: h2f(frag-order) = hln[NC,1024] @ w2t[256,1024]^T; A read once ----
__global__ __launch_bounds__(512) void k_gemm2(
    const _Float16* __restrict__ A, const _Float16* __restrict__ BT,
    _Float16* __restrict__ h2f) {
    __shared__ _Float16 As[128 * 64];
    __shared__ _Float16 Bs[256 * 64];
    int tid = threadIdx.x;
    int lane = tid & 63, wid = tid >> 6;
    int wr = wid >> 2, wc = wid & 3;
    int l15 = lane & 15, l4 = lane >> 4;
    int r0 = blockIdx.x * 128;
    facc4 acc[4][4] = {};
    for (int kt = 0; kt < 1024; kt += 64) {
#pragma unroll
        for (int i = 0; i < 2; ++i) {
            int ch = tid + 512 * i;
            int row = ch >> 3, col16 = ch & 7;
            int sw = col16 ^ (row & 7);
            *reinterpret_cast<int4*>(&As[row * 64 + sw * 8]) =
                *reinterpret_cast<const int4*>(A + (size_t)(r0 + row) * 1024 + kt + col16 * 8);
        }
#pragma unroll
        for (int i = 0; i < 4; ++i) {
            int ch = tid + 512 * i;
            int row = ch >> 3, col16 = ch & 7;
            int sw = col16 ^ (row & 7);
            *reinterpret_cast<int4*>(&Bs[row * 64 + sw * 8]) =
                *reinterpret_cast<const int4*>(BT + (size_t)row * 1024 + kt + col16 * 8);
        }
        __syncthreads();
#pragma unroll
        for (int kk = 0; kk < 2; ++kk) {
            half8 af[4], bf[4];
#pragma unroll
            for (int f = 0; f < 4; ++f) {
                int arow = wr * 64 + f * 16 + l15;
                int ac = (kk * 4 + l4) ^ (arow & 7);
                af[f] = *reinterpret_cast<const half8*>(&As[arow * 64 + ac * 8]);
                int brow = wc * 64 + f * 16 + l15;
                int bc = (kk * 4 + l4) ^ (brow & 7);
                bf[f] = *reinterpret_cast<const half8*>(&Bs[brow * 64 + bc * 8]);
            }
#pragma unroll
            for (int fi = 0; fi < 4; ++fi)
#pragma unroll
                for (int fj = 0; fj < 4; ++fj)
                    acc[fi][fj] = __builtin_amdgcn_mfma_f32_16x16x32_f16(
                        af[fi], bf[fj], acc[fi][fj], 0, 0, 0);
        }
        __syncthreads();
    }
#pragma unroll
    for (int fi = 0; fi < 4; ++fi)
#pragma unroll
        for (int fj = 0; fj < 4; ++fj)
#pragma unroll
            for (int i = 0; i < 4; ++i) {
                int r = r0 + wr * 64 + fi * 16 + l4 * 4 + i;
                int cc = wc * 64 + fj * 16 + l15;
                int g = r >> 6, nl = r & 63;
                size_t dst = (size_t)g * 16384 +
                             (((cc >> 4) * 2 + (nl >> 5)) * 512 +
                              ((cc & 15) + 16 * ((nl >> 3) & 3)) * 8 + (nl & 7));
                h2f[dst] = (_Float16)acc[fi][fj][i];
            }
}

// --- merged layer-2 + scores + softmax + pool + emb (per graph) --------------
__global__ __launch_bounds__(512) void k_graph2f(
    const _Float16* __restrict__ h2f,
    const int* __restrict__ coff, const int* __restrict__ eid, const int* __restrict__ ei,
    const float* __restrict__ ead2, const float* __restrict__ as2,
    const float* __restrict__ ad2,
    const float* __restrict__ b2, const float* __restrict__ g2,
    const float* __restrict__ be2,
    const _Float16* __restrict__ wat, const float* __restrict__ va,
    const int* __restrict__ food, const float* __restrict__ emb,
    float* __restrict__ out, int E, int B, int g0) {
    __shared__ _Float16 hfL[64 * 256];       // 32 KB arena (aliases Pm/llds/slds)
    _Float16* Pm = hfL;                      // [0, 8192) bytes
    float* llds = reinterpret_cast<float*>(hfL + 4096);        // 1536 B
    int* slds = reinterpret_cast<int*>(hfL + 4096 + 768);      // 1536 B
    __shared__ float rsum[64], rsq[64], ss2L[64], sd2L[64];
    __shared__ float part[8][64];
    __shared__ float at[64];
    int g = blockIdx.x;
    int b = g0 + g;
    int ng = (g0 + g) * 64;
    int tid = threadIdx.x;
    int lane = tid & 63, wid = tid >> 6;
    int l15 = lane & 15, l4 = lane >> 4;
    int cbase = wid * 32;
    if (tid < 64) { rsum[tid] = 0.f; rsq[tid] = 0.f; ss2L[tid] = 0.f; sd2L[tid] = 0.f; }
    for (int i = tid; i < 64 * 64 / 8; i += 512)
        *reinterpret_cast<int4*>(&Pm[0] + i * 8) = int4{0, 0, 0, 0};
    __syncthreads();
    const _Float16* hg = h2f + (size_t)g * 16384;
    half8 bfr[2][2];
#pragma unroll
    for (int kk = 0; kk < 2; ++kk)
#pragma unroll
        for (int f = 0; f < 2; ++f)
            bfr[kk][f] = *reinterpret_cast<const half8*>(
                hg + ((((cbase + f * 16) >> 4) * 2 + kk) * 512 + lane * 8));
    float ps[2][8] = {}, pd[2][8] = {};
#pragma unroll
    for (int kk = 0; kk < 2; ++kk)
#pragma unroll
        for (int f = 0; f < 2; ++f) {
            int c = cbase + f * 16 + l15;
            float a2 = as2[c], d2 = ad2[c];
#pragma unroll
            for (int j = 0; j < 8; ++j) {
                float hv = (float)bfr[kk][f][j];
                ps[kk][j] += hv * a2;
                pd[kk][j] += hv * d2;
            }
        }
#pragma unroll
    for (int kk = 0; kk < 2; ++kk)
#pragma unroll
        for (int j = 0; j < 8; ++j) {
            float s = ps[kk][j], d = pd[kk][j];
            s += __shfl_xor(s, 1); d += __shfl_xor(d, 1);
            s += __shfl_xor(s, 2); d += __shfl_xor(d, 2);
            s += __shfl_xor(s, 4); d += __shfl_xor(d, 4);
            s += __shfl_xor(s, 8); d += __shfl_xor(d, 8);
            if (l15 == 0) {
                int n = kk * 32 + l4 * 8 + j;
                atomicAdd(&ss2L[n], s);
                atomicAdd(&sd2L[n], d);
            }
        }
    __syncthreads();
    int pbase = coff[ng];
    int pcnt = coff[ng + 64] - pbase;
    if (pcnt > 384) pcnt = 384;
    for (int p = tid; p < pcnt; p += 512) {
        int e = eid[pbase + p];
        int s, d;
        if (e < E) { s = ei[e]; d = ei[E + e]; } else { s = e - E; d = s; }
        slds[p] = s - ng;
        float v = ss2L[s - ng] + sd2L[d - ng] + ead2[e];
        llds[p] = (v > 0.f) ? v : LEAKY_SLOPE * v;
    }
    __syncthreads();
    if (tid < 64) {
        int dst = tid;
        int p0 = coff[ng + dst] - pbase, p1 = coff[ng + dst + 1] - pbase;
        float m = -1e30f;
        for (int p = p0; p < p1; ++p) m = fmaxf(m, llds[p]);
        float sm = 0.f;
        for (int p = p0; p < p1; ++p) sm += expf(llds[p] - m);
        float iv = 1.f / (sm + 1e-16f);
        for (int p = p0; p < p1; ++p) {
            int src = slds[p];
            int pos = dst * 64 + (((src >> 3) ^ (dst & 7)) << 3) + (src & 7);
            Pm[pos] = (_Float16)((float)Pm[pos] + expf(llds[p] - m) * iv);
        }
    }
    __syncthreads();
    // MFMA: hf[dst][c] = P @ h2
    facc4 acc[4][2] = {};
#pragma unroll
    for (int kk = 0; kk < 2; ++kk) {
        half8 af[4];
#pragma unroll
        for (int f = 0; f < 4; ++f) {
            int arow = f * 16 + l15;
            af[f] = *reinterpret_cast<const half8*>(
                &Pm[arow * 64 + (((kk * 4 + l4) ^ (arow & 7)) << 3)]);
        }
#pragma unroll
        for (int fi = 0; fi < 4; ++fi)
#pragma unroll
            for (int fj = 0; fj < 2; ++fj)
                acc[fi][fj] = __builtin_amdgcn_mfma_f32_16x16x32_f16(
                    af[fi], bfr[kk][fj], acc[fi][fj], 0, 0, 0);
    }
    float bb[2];
#pragma unroll
    for (int fj = 0; fj < 2; ++fj) bb[fj] = b2[cbase + fj * 16 + l15];
#pragma unroll
    for (int fi = 0; fi < 4; ++fi)
#pragma unroll
        for (int i = 0; i < 4; ++i) {
            float s = 0.f, q = 0.f;
#pragma unroll
            for (int fj = 0; fj < 2; ++fj) {
                float v = acc[fi][fj][i] + bb[fj];
                acc[fi][fj][i] = v;
                s += v; q += v * v;
            }
            s += __shfl_xor(s, 1); q += __shfl_xor(q, 1);
            s += __shfl_xor(s, 2); q += __shfl_xor(q, 2);
            s += __shfl_xor(s, 4); q += __shfl_xor(q, 4);
            s += __shfl_xor(s, 8); q += __shfl_xor(q, 8);
            if (l15 == 0) {
                int r = fi * 16 + l4 * 4 + i;
                atomicAdd(&rsum[r], s);
                atomicAdd(&rsq[r], q);
            }
        }
    __syncthreads();    // also orders: Pm/llds/slds reads done before hfL writes
    // LN apply: keep f32 in acc; write f16 to hfL in scores-fragment order
#pragma unroll
    for (int fi = 0; fi < 4; ++fi)
#pragma unroll
        for (int i = 0; i < 4; ++i) {
            int rl = l4 * 4 + i;                 // row & 15
            float mu = rsum[fi * 16 + rl] * (1.f / 256.f);
            float var = rsq[fi * 16 + rl] * (1.f / 256.f) - mu * mu;
            float rstd = rsqrtf(var + 1e-5f);
#pragma unroll
            for (int fj = 0; fj < 2; ++fj) {
                int c = cbase + fj * 16 + l15;
                float v = (acc[fi][fj][i] - mu) * rstd * g2[c] + be2[c];
                acc[fi][fj][i] = v;              // keep f32 for pooling
                int idx = (fi * 8 + wid) * 512 +
                          ((fj * 2 + (l15 >> 3)) * 16 + rl) * 8 + (l15 & 7);
                hfL[idx] = (_Float16)v;
            }
        }
    __syncthreads();
    // scores GEMM: hfL(LDS fragments) @ wat^T
    facc4 acc2[4][2] = {};
#pragma unroll
    for (int kk = 0; kk < 8; ++kk) {
        half8 af[4], bf[2];
#pragma unroll
        for (int f = 0; f < 4; ++f)
            af[f] = *reinterpret_cast<const half8*>(&hfL[(f * 8 + kk) * 512 + lane * 8]);
#pragma unroll
        for (int f = 0; f < 2; ++f)
            bf[f] = *reinterpret_cast<const half8*>(
                wat + (((wid * 2 + f) * 8 + kk) * 512 + lane * 8));
#pragma unroll
        for (int fi = 0; fi < 4; ++fi)
#pragma unroll
            for (int fj = 0; fj < 2; ++fj)
                acc2[fi][fj] = __builtin_amdgcn_mfma_f32_16x16x32_f16(
                    af[fi], bf[fj], acc2[fi][fj], 0, 0, 0);
    }
    float vac[2];
#pragma unroll
    for (int fj = 0; fj < 2; ++fj) vac[fj] = va[cbase + fj * 16 + l15];
#pragma unroll
    for (int fi = 0; fi < 4; ++fi)
#pragma unroll
        for (int i = 0; i < 4; ++i) {
            float v = tanhf(acc2[fi][0][i]) * vac[0] + tanhf(acc2[fi][1][i]) * vac[1];
            v += __shfl_xor(v, 1); v += __shfl_xor(v, 2);
            v += __shfl_xor(v, 4); v += __shfl_xor(v, 8);
            if (l15 == 0) part[wid][fi * 16 + l4 * 4 + i] = v;
        }
    __syncthreads();
    if (tid < 64) {
        float sc = part[0][tid] + part[1][tid] + part[2][tid] + part[3][tid] +
                   part[4][tid] + part[5][tid] + part[6][tid] + part[7][tid];
        float m = sc;
        for (int o = 32; o; o >>= 1) m = fmaxf(m, __shfl_xor(m, o));
        float ex = expf(sc - m);
        float s = ex;
        for (int o = 32; o; o >>= 1) s += __shfl_xor(s, o);
        float a = ex / (s + 1e-16f);
        at[tid] = a;
        out[(size_t)B * 512 + (size_t)b * 64 + tid] = a;      // attn
    }
    __syncthreads();
    // pool from live f32 acc: per channel max over rows of hf*at
#pragma unroll
    for (int fj = 0; fj < 2; ++fj) {
        float m = -1e30f;
#pragma unroll
        for (int fi = 0; fi < 4; ++fi)
#pragma unroll
            for (int i = 0; i < 4; ++i) {
                int r = fi * 16 + l4 * 4 + i;
                m = fmaxf(m, acc[fi][fj][i] * at[r]);
            }
        m = fmaxf(m, __shfl_xor(m, 16));
        m = fmaxf(m, __shfl_xor(m, 32));
        if (l4 == 0)
            out[(size_t)b * 256 + cbase + fj * 16 + l15] = m;  // drug_fea
    }
    if (tid < 256)
        out[(size_t)B * 256 + (size_t)b * 256 + tid] =
            emb[(size_t)food[b] * 256 + tid];                  // food_fea
}

// ---------------------------------------------------------------------------
extern "C" void kernel_launch(void* const* d_in, const int* in_sizes, int n_in,
                              void* d_out, int out_size, void* d_ws, size_t ws_size,
                              hipStream_t stream) {
    const float* x   = (const float*)d_in[0];
    const float* ea  = (const float*)d_in[1];
    const int*   ei  = (const int*)d_in[2];
    const int*   food= (const int*)d_in[4];
    const float* W1  = (const float*)d_in[5];
    const float* as1 = (const float*)d_in[6];
    const float* ad1 = (const float*)d_in[7];
    const float* We1 = (const float*)d_in[8];
    const float* ae1 = (const float*)d_in[9];
    const float* b1  = (const float*)d_in[10];
    const float* g1  = (const float*)d_in[11];
    const float* be1 = (const float*)d_in[12];
    const float* W2  = (const float*)d_in[13];
    const float* as2 = (const float*)d_in[14];
    const float* ad2 = (const float*)d_in[15];
    const float* We2 = (const float*)d_in[16];
    const float* ae2 = (const float*)d_in[17];
    const float* b2  = (const float*)d_in[18];
    const float* g2  = (const float*)d_in[19];
    const float* be2 = (const float*)d_in[20];
    const float* Wa  = (const float*)d_in[21];
    const float* va  = (const float*)d_in[22];
    const float* emb = (const float*)d_in[23];
    float* out = (float*)d_out;

    const int N  = in_sizes[0] / 55;
    const int E  = in_sizes[2] / 2;
    const int B  = in_sizes[4];
    const int Ef = E + N;
    const int LPG = N / B;

    char* w = (char*)d_ws;
    size_t off = 0;
    auto take = [&](size_t bytes) -> char* {
        char* p = w + off;
        off = (off + bytes + 255) & ~(size_t)255;
        return p;
    };
    int*      coff = (int*)take((size_t)(N + 1) * 4);
    int*      eid  = (int*)take((size_t)Ef * 4);
    float*    ead1 = (float*)take((size_t)Ef * 4 * 4);
    float*    ead2 = (float*)take((size_t)Ef * 4);
    float*    fold = (float*)take(4096 * 4);
    float*    ss1  = (float*)take((size_t)N * 4 * 4);
    float*    sd1  = (float*)take((size_t)N * 4 * 4);
    _Float16* xbf  = (_Float16*)take((size_t)N * 64 * 2);
    _Float16* w1f  = (_Float16*)take((size_t)1024 * 64 * 2);
    _Float16* w2t  = (_Float16*)take((size_t)256 * 1024 * 2);
    _Float16* wat  = (_Float16*)take((size_t)256 * 256 * 2);
    size_t smallEnd = off;

    int G = B;
    while (G > 2 && smallEnd + 2ull * G * 131072 + 768 > ws_size) G >>= 1;
    _Float16* hpre = (_Float16*)take((size_t)G * 131072);
    _Float16* hln  = (_Float16*)take((size_t)G * 131072);
    _Float16* h2f  = (_Float16*)hpre;       // overlay: hpre dead after k_ln1

    k_prep_w<<<(1024 * 64 + 256 * 1024 + 256 * 256 + 3072 + 255) / 256, 256, 0, stream>>>(
        W1, W2, Wa, We1, ae1, We2, ae2, as1, ad1, w1f, w2t, wat, fold);
    k_prep_x<<<(N * 64 + N + 255) / 256, 256, 0, stream>>>(
        x, fold + 64, fold + 320, xbf, ss1, sd1, N);
    k_graph_csr<<<B, 256, 0, stream>>>(ei, ea, fold, fold + 32, coff, eid,
                                       ead1, ead2, E, B);

    for (int g0 = 0; g0 < B; g0 += G) {
        int Gc = (g0 + G <= B) ? G : (B - g0);
        int NC = Gc * LPG;
        k_layer1<<<Gc, 512, 0, stream>>>(xbf, coff, eid, ei, ead1, ss1, sd1,
                                         w1f, hpre, E, g0);
        k_ln1<<<NC / 4, 256, 0, stream>>>(hpre, b1, g1, be1, hln);
        k_gemm2<<<NC / 128, 512, 0, stream>>>(hln, w2t, h2f);
        k_graph2f<<<Gc, 512, 0, stream>>>(h2f, coff, eid, ei, ead2, as2, ad2,
                                          b2, g2, be2, wat, va, food, emb,
                                          out, E, B, g0);
    }
}